// Round 2
// baseline (2190.816 us; speedup 1.0000x reference)
//
#include <hip/hip_runtime.h>
#include <hip/hip_bf16.h>

typedef __hip_bfloat16 bf16;

#define N_NODES 50000
#define NPAD    50048          // N rounded up (multiple of 64) so tile overreads stay in-buffer
#define E_EDGES 600000
#define HID     128
#define HEADS   4
#define TN      32             // nodes per GEMM block

// ---- monotonic float<->uint encoding for atomicMax on floats ----
__device__ __forceinline__ unsigned enc_f(float f) {
  unsigned u = __float_as_uint(f);
  return (u & 0x80000000u) ? ~u : (u | 0x80000000u);
}
__device__ __forceinline__ float dec_f(unsigned e) {
  unsigned u = (e & 0x80000000u) ? (e & 0x7fffffffu) : ~e;
  return __uint_as_float(u);
}

// ---- runtime dtype detection ----
// flags[0]=1 -> float tensors are fp32 (else bf16). flags[1]=1 -> indices are int64.
__global__ __launch_bounds__(256) void detect_kernel(const unsigned short* __restrict__ xb,
                                                     const int* __restrict__ ei,
                                                     int* __restrict__ flags) {
  int t = threadIdx.x;
  __shared__ int cnt[2];
  if (t < 2) cnt[t] = 0;
  __syncthreads();
  // bf16 view, EVEN index: real bf16 data -> exponent near 127; fp32-underlying ->
  // this is the low mantissa half of an fp32 word, exponent ~uniform.
  unsigned short v = xb[2 * t];
  int ex = (v >> 7) & 0xFF;
  if (ex < 119 || ex > 135) atomicAdd(&cnt[0], 1);
  // int64 indices: odd int32 words are high halves == 0 (ids < 50000).
  if (ei[2 * t + 1] != 0) atomicAdd(&cnt[1], 1);
  __syncthreads();
  if (t == 0) {
    flags[0] = (cnt[0] > 64) ? 1 : 0;
    flags[1] = (cnt[1] == 0) ? 1 : 0;
  }
}

// ---- generic float-tensor conversion to fp32 ----
__global__ __launch_bounds__(256) void cvt_f_kernel(const void* __restrict__ src,
                                                    float* __restrict__ dst, int n,
                                                    const int* __restrict__ flags) {
  int i = blockIdx.x * 256 + threadIdx.x;
  if (i >= n) return;
  if (flags[0]) dst[i] = ((const float*)src)[i];
  else          dst[i] = __bfloat162float(((const bf16*)src)[i]);
}

// ---- index conversion to clean int32 arrays ----
__global__ __launch_bounds__(256) void cvt_idx_kernel(const int* __restrict__ eidx,
                                                      const int* __restrict__ etype,
                                                      int* __restrict__ srcA, int* __restrict__ dstA,
                                                      int* __restrict__ etA,
                                                      const int* __restrict__ flags) {
  int e = blockIdx.x * 256 + threadIdx.x;
  if (e >= E_EDGES) return;
  if (flags[1]) {
    const long long* e64 = (const long long*)eidx;
    const long long* t64 = (const long long*)etype;
    srcA[e] = (int)e64[e];
    dstA[e] = (int)e64[E_EDGES + e];
    etA[e]  = (int)t64[e];
  } else {
    srcA[e] = eidx[e];
    dstA[e] = eidx[E_EDGES + e];
    etA[e]  = etype[e];
  }
}

__global__ __launch_bounds__(256) void zero_kernel(float* __restrict__ p, int n) {
  int i = blockIdx.x * 256 + threadIdx.x;
  if (i < n) p[i] = 0.f;
}

// ---- xw[r,n,:] = h[n,:] @ W[r]  (fp32 in, bf16 out) ----
__global__ __launch_bounds__(128) void gemm_xw_kernel(const float* __restrict__ h,
                                                      const float* __restrict__ Wf,
                                                      bf16* __restrict__ xw) {
  const int r  = blockIdx.y;
  const int n0 = blockIdx.x * TN;
  const int o  = threadIdx.x;            // output channel 0..127
  const float* Wr = Wf + r * HID * HID;
  float acc[TN];
#pragma unroll
  for (int n = 0; n < TN; ++n) acc[n] = 0.f;
  const float* hb = h + (size_t)n0 * HID;
  for (int i = 0; i < HID; ++i) {
    float w = Wr[i * HID + o];                     // coalesced across threads
#pragma unroll
    for (int n = 0; n < TN; ++n)                   // hb[...] is wave-uniform -> s_load
      acc[n] = fmaf(hb[n * HID + i], w, acc[n]);
  }
  bf16* out = xw + ((size_t)r * NPAD + n0) * HID + o;
  int nmax = N_NODES - n0; if (nmax > TN) nmax = TN;
  for (int n = 0; n < nmax; ++n) out[n * HID] = __float2bfloat16(acc[n]);
}

// ---- qi[r,n,h] = xw[r,n,:]·Q[:,h]; kj likewise with K.  One wave per (r,n). ----
__global__ __launch_bounds__(256) void qk_kernel(const bf16* __restrict__ xw,
                                                 const float* __restrict__ Qf,
                                                 const float* __restrict__ Kf,
                                                 float* __restrict__ qi,
                                                 float* __restrict__ kj) {
  int w    = blockIdx.x * 4 + (threadIdx.x >> 6);  // row index r*NPAD+n
  int lane = threadIdx.x & 63;
  if (w >= 2 * NPAD) return;
  const bf16* row = xw + (size_t)w * HID;
  float x0 = __bfloat162float(row[lane]);
  float x1 = __bfloat162float(row[lane + 64]);
  float pq[HEADS], pk[HEADS];
#pragma unroll
  for (int hh = 0; hh < HEADS; ++hh) {
    pq[hh] = x0 * Qf[lane * HEADS + hh] + x1 * Qf[(lane + 64) * HEADS + hh];
    pk[hh] = x0 * Kf[lane * HEADS + hh] + x1 * Kf[(lane + 64) * HEADS + hh];
  }
#pragma unroll
  for (int off = 32; off > 0; off >>= 1) {
#pragma unroll
    for (int hh = 0; hh < HEADS; ++hh) {
      pq[hh] += __shfl_down(pq[hh], off);
      pk[hh] += __shfl_down(pk[hh], off);
    }
  }
  if (lane == 0) {
#pragma unroll
    for (int hh = 0; hh < HEADS; ++hh) {
      qi[(size_t)w * HEADS + hh] = pq[hh];
      kj[(size_t)w * HEADS + hh] = pk[hh];
    }
  }
}

// ---- per-edge: alpha = leaky_relu(qi[r,d]+kj[r,s]); atomicMax into m ----
__global__ __launch_bounds__(256) void edge_alpha_max_kernel(
    const int* __restrict__ srcA, const int* __restrict__ dstA, const int* __restrict__ etA,
    const float* __restrict__ qi, const float* __restrict__ kj,
    float* __restrict__ ae, unsigned* __restrict__ menc) {
  int e = blockIdx.x * 256 + threadIdx.x;
  if (e >= E_EDGES) return;
  int s = srcA[e], d = dstA[e], r = etA[e];
  const float4 q4 = *(const float4*)(qi + ((size_t)r * NPAD + d) * HEADS);
  const float4 k4 = *(const float4*)(kj + ((size_t)r * NPAD + s) * HEADS);
  float a[4] = {q4.x + k4.x, q4.y + k4.y, q4.z + k4.z, q4.w + k4.w};
  float4 st;
  float* stp = &st.x;
#pragma unroll
  for (int hh = 0; hh < 4; ++hh) {
    float v = a[hh];
    v = v >= 0.f ? v : 0.2f * v;
    stp[hh] = v;
    atomicMax(&menc[d * HEADS + hh], enc_f(v));
  }
  *(float4*)(ae + (size_t)e * HEADS) = st;
}

// ---- per-edge: e = exp(alpha - m[d]); atomicAdd into s[d] ----
__global__ __launch_bounds__(256) void edge_exp_sum_kernel(
    const int* __restrict__ dstA, float* __restrict__ ae,
    const unsigned* __restrict__ menc, float* __restrict__ ssum) {
  int e = blockIdx.x * 256 + threadIdx.x;
  if (e >= E_EDGES) return;
  int d = dstA[e];
  float4 a4 = *(const float4*)(ae + (size_t)e * HEADS);
  const unsigned* mp = menc + (size_t)d * HEADS;
  float e0 = __expf(a4.x - dec_f(mp[0]));
  float e1 = __expf(a4.y - dec_f(mp[1]));
  float e2 = __expf(a4.z - dec_f(mp[2]));
  float e3 = __expf(a4.w - dec_f(mp[3]));
  *(float4*)(ae + (size_t)e * HEADS) = make_float4(e0, e1, e2, e3);
  atomicAdd(&ssum[d * HEADS + 0], e0);
  atomicAdd(&ssum[d * HEADS + 1], e1);
  atomicAdd(&ssum[d * HEADS + 2], e2);
  atomicAdd(&ssum[d * HEADS + 3], e3);
}

// ---- per-edge scatter: agg[d,:] += xw[r,s,:] * a[head(c)] ----
__global__ __launch_bounds__(256) void edge_agg_kernel(
    const int* __restrict__ srcA, const int* __restrict__ dstA, const int* __restrict__ etA,
    const float* __restrict__ ae, const float* __restrict__ ssum,
    const bf16* __restrict__ xw, float* __restrict__ agg) {
  int e = blockIdx.x * 2 + (threadIdx.x >> 7);
  if (e >= E_EDGES) return;
  int c = threadIdx.x & 127;
  int s = srcA[e], d = dstA[e], r = etA[e];
  int hh = c >> 5;
  float a = ae[(size_t)e * HEADS + hh] / (ssum[(size_t)d * HEADS + hh] + 1e-16f);
  float v = __bfloat162float(xw[((size_t)r * NPAD + s) * HID + c]) * a;
  atomicAdd(&agg[(size_t)d * HID + c], v);
}

// ---- fold pW transpose + (cb@pW.T + pb) bias, fp32 ----
__global__ __launch_bounds__(128) void prep_proj_kernel(const float* __restrict__ pW,
                                                        const float* __restrict__ cb,
                                                        const float* __restrict__ pb,
                                                        float* __restrict__ pWT,
                                                        float* __restrict__ bo) {
  int o = threadIdx.x;
  float acc = pb[o];
  for (int i = 0; i < HID; ++i) {
    float w = pW[o * HID + i];
    pWT[i * HID + o] = w;
    acc += cb[i] * w;
  }
  bo[o] = acc;
}

// ---- out[n,o] = elu( agg[n,:]·pWT[:,o] + bo[o] ) ----
__global__ __launch_bounds__(128) void proj_kernel(const float* __restrict__ agg,
                                                   const float* __restrict__ pWT,
                                                   const float* __restrict__ bo,
                                                   float* __restrict__ hout,
                                                   void* __restrict__ dout,
                                                   const int* __restrict__ flags) {
  const int n0 = blockIdx.x * TN;
  const int o  = threadIdx.x;
  const int f32out = flags[0];
  float acc[TN];
#pragma unroll
  for (int n = 0; n < TN; ++n) acc[n] = 0.f;
  const float* ab = agg + (size_t)n0 * HID;
  for (int i = 0; i < HID; ++i) {
    float w = pWT[i * HID + o];
#pragma unroll
    for (int n = 0; n < TN; ++n)
      acc[n] = fmaf(ab[n * HID + i], w, acc[n]);
  }
  float b = bo[o];
  int nmax = N_NODES - n0; if (nmax > TN) nmax = TN;
  for (int n = 0; n < nmax; ++n) {
    float v = acc[n] + b;
    v = v > 0.f ? v : expm1f(v);       // ELU (alpha=1)
    size_t idx = (size_t)(n0 + n) * HID + o;
    if (dout) {
      if (f32out) ((float*)dout)[idx] = v;
      else        ((bf16*)dout)[idx]  = __float2bfloat16(v);
    } else {
      hout[idx] = v;
    }
  }
}

extern "C" void kernel_launch(void* const* d_in, const int* in_sizes, int n_in,
                              void* d_out, int out_size, void* d_ws, size_t ws_size,
                              hipStream_t stream) {
  const void* x     = d_in[0];
  const int*  eidx  = (const int*)d_in[1];
  const int*  etype = (const int*)d_in[2];

  float* ws = (float*)d_ws;
  size_t off = 0;
  int*   flags = (int*)(ws + off); off += 16;
  float* h    = ws + off; off += (size_t)NPAD * HID;            // fp32 node features
  bf16*  xw   = (bf16*)(ws + off); off += (size_t)NPAD * HID;   // bf16 [2,NPAD,128]
  float* qi   = ws + off; off += (size_t)2 * NPAD * HEADS;
  float* kj   = ws + off; off += (size_t)2 * NPAD * HEADS;
  unsigned* menc = (unsigned*)(ws + off); off += (size_t)NPAD * HEADS;   // contiguous zero
  float* ssum = ws + off; off += (size_t)NPAD * HEADS;                   // region:
  float* agg  = ws + off; off += (size_t)NPAD * HID;                     // menc|ssum|agg
  float* ae   = ws + off; off += (size_t)E_EDGES * HEADS;
  int* srcA = (int*)(ws + off); off += E_EDGES;
  int* dstA = (int*)(ws + off); off += E_EDGES;
  int* etA  = (int*)(ws + off); off += E_EDGES;
  float* Wf  = ws + off; off += (size_t)2 * 2 * HID * HID;   // [layer][rel][128][128]
  float* Qf  = ws + off; off += 2 * HID * HEADS;
  float* Kf  = ws + off; off += 2 * HID * HEADS;
  float* cbf = ws + off; off += 2 * HID;
  float* pbf = ws + off; off += 2 * HID;
  float* pWf = ws + off; off += (size_t)2 * HID * HID;
  float* pWT = ws + off; off += HID * HID;
  float* bo  = ws + off; off += HID;

  detect_kernel<<<1, 256, 0, stream>>>((const unsigned short*)x, eidx, flags);
  cvt_idx_kernel<<<(E_EDGES + 255) / 256, 256, 0, stream>>>(eidx, etype, srcA, dstA, etA, flags);

  cvt_f_kernel<<<(N_NODES * HID + 255) / 256, 256, 0, stream>>>(x, h, N_NODES * HID, flags);
  const int pidx[2][5] = {{3, 4, 5, 6, 8}, {9, 10, 11, 12, 14}};  // W,Q,K,cb,pb
  for (int l = 0; l < 2; ++l) {
    cvt_f_kernel<<<(2 * HID * HID + 255) / 256, 256, 0, stream>>>(d_in[pidx[l][0]], Wf + (size_t)l * 2 * HID * HID, 2 * HID * HID, flags);
    cvt_f_kernel<<<(HID * HEADS + 255) / 256, 256, 0, stream>>>(d_in[pidx[l][1]], Qf + l * HID * HEADS, HID * HEADS, flags);
    cvt_f_kernel<<<(HID * HEADS + 255) / 256, 256, 0, stream>>>(d_in[pidx[l][2]], Kf + l * HID * HEADS, HID * HEADS, flags);
    cvt_f_kernel<<<1, 256, 0, stream>>>(d_in[pidx[l][3]], cbf + l * HID, HID, flags);
    cvt_f_kernel<<<1, 256, 0, stream>>>(d_in[pidx[l][4]], pbf + l * HID, HID, flags);
    cvt_f_kernel<<<(HID * HID + 255) / 256, 256, 0, stream>>>(d_in[l == 0 ? 7 : 13], pWf + (size_t)l * HID * HID, HID * HID, flags);
  }

  const int zeroN = NPAD * (HEADS + HEADS + HID);   // menc+ssum+agg contiguous
  for (int l = 0; l < 2; ++l) {
    dim3 g1((N_NODES + TN - 1) / TN, 2);
    gemm_xw_kernel<<<g1, 128, 0, stream>>>(h, Wf + (size_t)l * 2 * HID * HID, xw);
    qk_kernel<<<(2 * NPAD + 3) / 4, 256, 0, stream>>>(xw, Qf + l * HID * HEADS, Kf + l * HID * HEADS, qi, kj);
    zero_kernel<<<(zeroN + 255) / 256, 256, 0, stream>>>((float*)menc, zeroN);
    edge_alpha_max_kernel<<<(E_EDGES + 255) / 256, 256, 0, stream>>>(srcA, dstA, etA, qi, kj, ae, menc);
    edge_exp_sum_kernel<<<(E_EDGES + 255) / 256, 256, 0, stream>>>(dstA, ae, menc, ssum);
    edge_agg_kernel<<<(E_EDGES + 1) / 2, 256, 0, stream>>>(srcA, dstA, etA, ae, ssum, xw, agg);
    prep_proj_kernel<<<1, 128, 0, stream>>>(pWf + (size_t)l * HID * HID, cbf + l * HID, pbf + l * HID, pWT, bo);
    proj_kernel<<<(N_NODES + TN - 1) / TN, 128, 0, stream>>>(
        agg, pWT, bo, h, (l == 1) ? d_out : nullptr, flags);
  }
}

// Round 3
// 1370.466 us; speedup vs baseline: 1.5986x; 1.5986x over previous
//
#include <hip/hip_runtime.h>
#include <hip/hip_bf16.h>

typedef __hip_bfloat16 bf16;
typedef short s16x8 __attribute__((ext_vector_type(8)));
typedef float f32x4 __attribute__((ext_vector_type(4)));

#define N_NODES 50000
#define NPAD    50048          // multiple of 64
#define E_EDGES 600000
#define HID     128
#define HEADS   4

// ---- float -> bf16 bits (RNE), finite inputs only ----
__device__ __forceinline__ unsigned short f2bf_bits(float f) {
  unsigned u = __float_as_uint(f);
  u += 0x7fffu + ((u >> 16) & 1u);
  return (unsigned short)(u >> 16);
}
__device__ __forceinline__ float bf2f(unsigned short b) {
  return __uint_as_float(((unsigned)b) << 16);
}

// ---- monotonic float<->uint encoding for atomicMax on floats ----
__device__ __forceinline__ unsigned enc_f(float f) {
  unsigned u = __float_as_uint(f);
  return (u & 0x80000000u) ? ~u : (u | 0x80000000u);
}
__device__ __forceinline__ float dec_f(unsigned e) {
  unsigned u = (e & 0x80000000u) ? (e & 0x7fffffffu) : ~e;
  return __uint_as_float(u);
}

// ---- runtime dtype detection ----
// flags[0]=1 -> float tensors are fp32 (else bf16). flags[1]=1 -> indices are int64.
__global__ __launch_bounds__(256) void detect_kernel(const unsigned short* __restrict__ xb,
                                                     const int* __restrict__ ei,
                                                     int* __restrict__ flags) {
  int t = threadIdx.x;
  __shared__ int cnt[2];
  if (t < 2) cnt[t] = 0;
  __syncthreads();
  unsigned short v = xb[2 * t];
  int ex = (v >> 7) & 0xFF;
  if (ex < 119 || ex > 135) atomicAdd(&cnt[0], 1);
  if (ei[2 * t + 1] != 0) atomicAdd(&cnt[1], 1);
  __syncthreads();
  if (t == 0) {
    flags[0] = (cnt[0] > 64) ? 1 : 0;
    flags[1] = (cnt[1] == 0) ? 1 : 0;
  }
}

// ---- generic float-tensor conversion to fp32 ----
__global__ __launch_bounds__(256) void cvt_f_kernel(const void* __restrict__ src,
                                                    float* __restrict__ dst, int n,
                                                    const int* __restrict__ flags) {
  int i = blockIdx.x * 256 + threadIdx.x;
  if (i >= n) return;
  if (flags[0]) dst[i] = ((const float*)src)[i];
  else          dst[i] = bf2f(((const unsigned short*)src)[i]);
}

// ---- float-tensor -> bf16 bits ----
__global__ __launch_bounds__(256) void cvt_xb_kernel(const void* __restrict__ src,
                                                     unsigned short* __restrict__ dst, int n,
                                                     const int* __restrict__ flags) {
  int i = blockIdx.x * 256 + threadIdx.x;
  if (i >= n) return;
  if (flags[0]) dst[i] = f2bf_bits(((const float*)src)[i]);
  else          dst[i] = ((const unsigned short*)src)[i];
}

// ---- W [2][128(in)][128(out)] -> bf16 N-major Wbt [2][128(out)][128(in)] ----
__global__ __launch_bounds__(256) void cvt_wt_kernel(const void* __restrict__ src,
                                                     unsigned short* __restrict__ dst,
                                                     const int* __restrict__ flags) {
  int idx = blockIdx.x * 256 + threadIdx.x;
  if (idx >= 2 * HID * HID) return;
  int r = idx >> 14, i = (idx >> 7) & 127, o = idx & 127;
  unsigned short b;
  if (flags[0]) b = f2bf_bits(((const float*)src)[idx]);
  else          b = ((const unsigned short*)src)[idx];
  dst[((size_t)r * HID + o) * HID + i] = b;
}

// ---- index conversion to clean int32 arrays ----
__global__ __launch_bounds__(256) void cvt_idx_kernel(const int* __restrict__ eidx,
                                                      const int* __restrict__ etype,
                                                      int* __restrict__ srcA, int* __restrict__ dstA,
                                                      int* __restrict__ etA,
                                                      const int* __restrict__ flags) {
  int e = blockIdx.x * 256 + threadIdx.x;
  if (e >= E_EDGES) return;
  if (flags[1]) {
    const long long* e64 = (const long long*)eidx;
    const long long* t64 = (const long long*)etype;
    srcA[e] = (int)e64[e];
    dstA[e] = (int)e64[E_EDGES + e];
    etA[e]  = (int)t64[e];
  } else {
    srcA[e] = eidx[e];
    dstA[e] = eidx[E_EDGES + e];
    etA[e]  = etype[e];
  }
}

__global__ __launch_bounds__(256) void zero_kernel(float* __restrict__ p, int n) {
  int i = blockIdx.x * 256 + threadIdx.x;
  if (i < n) p[i] = 0.f;
}

// ================= MFMA GEMM core: one wave -> 64 rows x 64 cols, K=128 ======
// Ab: bf16 bits, row-major [*][128].  Bt: bf16 bits, N-major [n][128].
__device__ __forceinline__ void wave_gemm64(const unsigned short* __restrict__ Ab, int row0,
                                            const unsigned short* __restrict__ Bt, int colb,
                                            int lane, f32x4 acc[4][4]) {
  const int lm = lane & 15, q = lane >> 4;
#pragma unroll
  for (int kc = 0; kc < 4; ++kc) {
    const int ko = kc * 32 + q * 8;
    s16x8 af[4], bfr[4];
#pragma unroll
    for (int rt = 0; rt < 4; ++rt)
      af[rt] = *(const s16x8*)(Ab + (size_t)(row0 + rt * 16 + lm) * HID + ko);
#pragma unroll
    for (int ct = 0; ct < 4; ++ct)
      bfr[ct] = *(const s16x8*)(Bt + (size_t)(colb + ct * 16 + lm) * HID + ko);
#pragma unroll
    for (int rt = 0; rt < 4; ++rt)
#pragma unroll
      for (int ct = 0; ct < 4; ++ct)
        acc[rt][ct] = __builtin_amdgcn_mfma_f32_16x16x32_bf16(af[rt], bfr[ct], acc[rt][ct], 0, 0, 0);
  }
}

// ---- xw[r,n,:] = h[n,:] @ W[r]  (bf16 mfma) ----
__global__ __launch_bounds__(256) void gemm_xw_mfma(const unsigned short* __restrict__ hb,
                                                    const unsigned short* __restrict__ Wbt,  // [2][o][i]
                                                    bf16* __restrict__ xw) {
  const int wave = threadIdx.x >> 6, lane = threadIdx.x & 63;
  const int row0 = blockIdx.y * 256 + wave * 64;
  if (row0 >= NPAD) return;
  const int bn = blockIdx.x;                 // 0..3 ; panels first for L2 reuse of A rows
  const int r = bn >> 1, colb = (bn & 1) * 64;
  f32x4 acc[4][4];
#pragma unroll
  for (int a = 0; a < 4; ++a)
#pragma unroll
    for (int b = 0; b < 4; ++b) { f32x4 z = {0.f, 0.f, 0.f, 0.f}; acc[a][b] = z; }
  wave_gemm64(hb, row0, Wbt + (size_t)r * HID * HID, colb, lane, acc);
  const int lm = lane & 15, q = lane >> 4;
#pragma unroll
  for (int rt = 0; rt < 4; ++rt)
#pragma unroll
    for (int i = 0; i < 4; ++i) {
      int row = row0 + rt * 16 + q * 4 + i;
      if (row < N_NODES) {
#pragma unroll
        for (int ct = 0; ct < 4; ++ct) {
          int o = colb + ct * 16 + lm;
          xw[((size_t)r * NPAD + row) * HID + o] = __float2bfloat16(acc[rt][ct][i]);
        }
      }
    }
}

// ---- out[n,o] = elu( agg[n,:] @ pW.T + bo ), dual-dtype output ----
__global__ __launch_bounds__(256) void proj_mfma(const unsigned short* __restrict__ aggb,
                                                 const unsigned short* __restrict__ pWTb, // [o][i]
                                                 const float* __restrict__ bo,
                                                 unsigned short* __restrict__ hbout,      // layer0: next-layer bf16 input
                                                 void* __restrict__ dout,                 // layer1: final out
                                                 const int* __restrict__ flags) {
  const int wave = threadIdx.x >> 6, lane = threadIdx.x & 63;
  const int row0 = blockIdx.y * 256 + wave * 64;
  if (row0 >= NPAD) return;
  const int colb = blockIdx.x * 64;          // 0..1
  f32x4 acc[4][4];
#pragma unroll
  for (int a = 0; a < 4; ++a)
#pragma unroll
    for (int b = 0; b < 4; ++b) { f32x4 z = {0.f, 0.f, 0.f, 0.f}; acc[a][b] = z; }
  wave_gemm64(aggb, row0, pWTb, colb, lane, acc);
  const int lm = lane & 15, q = lane >> 4;
  const int f32out = flags[0];
#pragma unroll
  for (int rt = 0; rt < 4; ++rt)
#pragma unroll
    for (int i = 0; i < 4; ++i) {
      int row = row0 + rt * 16 + q * 4 + i;
      if (row < N_NODES) {
#pragma unroll
        for (int ct = 0; ct < 4; ++ct) {
          int o = colb + ct * 16 + lm;
          float v = acc[rt][ct][i] + bo[o];
          v = v > 0.f ? v : expm1f(v);       // ELU
          size_t idx = (size_t)row * HID + o;
          if (dout) {
            if (f32out) ((float*)dout)[idx] = v;
            else        ((unsigned short*)dout)[idx] = f2bf_bits(v);
          } else {
            hbout[idx] = f2bf_bits(v);
          }
        }
      }
    }
}

// ---- qi[r,n,h] = xw[r,n,:]·Q[:,h]; kj likewise with K.  One wave per (r,n). ----
__global__ __launch_bounds__(256) void qk_kernel(const bf16* __restrict__ xw,
                                                 const float* __restrict__ Qf,
                                                 const float* __restrict__ Kf,
                                                 float* __restrict__ qi,
                                                 float* __restrict__ kj) {
  int w    = blockIdx.x * 4 + (threadIdx.x >> 6);
  int lane = threadIdx.x & 63;
  if (w >= 2 * NPAD) return;
  const bf16* row = xw + (size_t)w * HID;
  float x0 = __bfloat162float(row[lane]);
  float x1 = __bfloat162float(row[lane + 64]);
  float pq[HEADS], pk[HEADS];
#pragma unroll
  for (int hh = 0; hh < HEADS; ++hh) {
    pq[hh] = x0 * Qf[lane * HEADS + hh] + x1 * Qf[(lane + 64) * HEADS + hh];
    pk[hh] = x0 * Kf[lane * HEADS + hh] + x1 * Kf[(lane + 64) * HEADS + hh];
  }
#pragma unroll
  for (int off = 32; off > 0; off >>= 1) {
#pragma unroll
    for (int hh = 0; hh < HEADS; ++hh) {
      pq[hh] += __shfl_down(pq[hh], off);
      pk[hh] += __shfl_down(pk[hh], off);
    }
  }
  if (lane == 0) {
#pragma unroll
    for (int hh = 0; hh < HEADS; ++hh) {
      qi[(size_t)w * HEADS + hh] = pq[hh];
      kj[(size_t)w * HEADS + hh] = pk[hh];
    }
  }
}

// ---- per-edge: alpha = leaky_relu(qi[r,d]+kj[r,s]); atomicMax into m ----
__global__ __launch_bounds__(256) void edge_alpha_max_kernel(
    const int* __restrict__ srcA, const int* __restrict__ dstA, const int* __restrict__ etA,
    const float* __restrict__ qi, const float* __restrict__ kj,
    float* __restrict__ ae, unsigned* __restrict__ menc) {
  int e = blockIdx.x * 256 + threadIdx.x;
  if (e >= E_EDGES) return;
  int s = srcA[e], d = dstA[e], r = etA[e];
  const float4 q4 = *(const float4*)(qi + ((size_t)r * NPAD + d) * HEADS);
  const float4 k4 = *(const float4*)(kj + ((size_t)r * NPAD + s) * HEADS);
  float a[4] = {q4.x + k4.x, q4.y + k4.y, q4.z + k4.z, q4.w + k4.w};
  float4 st;
  float* stp = &st.x;
#pragma unroll
  for (int hh = 0; hh < 4; ++hh) {
    float v = a[hh];
    v = v >= 0.f ? v : 0.2f * v;
    stp[hh] = v;
    atomicMax(&menc[d * HEADS + hh], enc_f(v));
  }
  *(float4*)(ae + (size_t)e * HEADS) = st;
}

// ---- per-edge: e = exp(alpha - m[d]); atomicAdd into s[d] ----
__global__ __launch_bounds__(256) void edge_exp_sum_kernel(
    const int* __restrict__ dstA, float* __restrict__ ae,
    const unsigned* __restrict__ menc, float* __restrict__ ssum) {
  int e = blockIdx.x * 256 + threadIdx.x;
  if (e >= E_EDGES) return;
  int d = dstA[e];
  float4 a4 = *(const float4*)(ae + (size_t)e * HEADS);
  const unsigned* mp = menc + (size_t)d * HEADS;
  float e0 = __expf(a4.x - dec_f(mp[0]));
  float e1 = __expf(a4.y - dec_f(mp[1]));
  float e2 = __expf(a4.z - dec_f(mp[2]));
  float e3 = __expf(a4.w - dec_f(mp[3]));
  *(float4*)(ae + (size_t)e * HEADS) = make_float4(e0, e1, e2, e3);
  atomicAdd(&ssum[d * HEADS + 0], e0);
  atomicAdd(&ssum[d * HEADS + 1], e1);
  atomicAdd(&ssum[d * HEADS + 2], e2);
  atomicAdd(&ssum[d * HEADS + 3], e3);
}

// ---- per-edge scatter: agg[d,:] += xw[r,s,:] * a[head(c)] ----
__global__ __launch_bounds__(256) void edge_agg_kernel(
    const int* __restrict__ srcA, const int* __restrict__ dstA, const int* __restrict__ etA,
    const float* __restrict__ ae, const float* __restrict__ ssum,
    const bf16* __restrict__ xw, float* __restrict__ agg) {
  int e = blockIdx.x * 2 + (threadIdx.x >> 7);
  if (e >= E_EDGES) return;
  int c = threadIdx.x & 127;
  int s = srcA[e], d = dstA[e], r = etA[e];
  int hh = c >> 5;
  float a = ae[(size_t)e * HEADS + hh] / (ssum[(size_t)d * HEADS + hh] + 1e-16f);
  float v = __bfloat162float(xw[((size_t)r * NPAD + s) * HID + c]) * a;
  atomicAdd(&agg[(size_t)d * HID + c], v);
}

// ---- fold bias: bo = pb + cb @ pW.T ; pWTb[o][i] = bf16(pW[o][i]) ----
__global__ __launch_bounds__(128) void prep_proj_kernel(const float* __restrict__ pW,
                                                        const float* __restrict__ cb,
                                                        const float* __restrict__ pb,
                                                        unsigned short* __restrict__ pWTb,
                                                        float* __restrict__ bo) {
  int o = threadIdx.x;
  float acc = pb[o];
  for (int i = 0; i < HID; ++i) {
    float w = pW[o * HID + i];
    pWTb[o * HID + i] = f2bf_bits(w);
    acc += cb[i] * w;
  }
  bo[o] = acc;
}

// ---- agg fp32 -> bf16 bits ----
__global__ __launch_bounds__(256) void cast_aggb_kernel(const float* __restrict__ agg,
                                                        unsigned short* __restrict__ aggb) {
  int i = blockIdx.x * 256 + threadIdx.x;
  if (i < NPAD * HID) aggb[i] = f2bf_bits(agg[i]);
}

extern "C" void kernel_launch(void* const* d_in, const int* in_sizes, int n_in,
                              void* d_out, int out_size, void* d_ws, size_t ws_size,
                              hipStream_t stream) {
  const void* x     = d_in[0];
  const int*  eidx  = (const int*)d_in[1];
  const int*  etype = (const int*)d_in[2];

  float* ws = (float*)d_ws;
  size_t off = 0;
  int*   flags = (int*)(ws + off); off += 16;
  unsigned short* hb   = (unsigned short*)(ws + off); off += (size_t)NPAD * HID / 2;   // bf16 [NPAD][128]
  bf16*  xw   = (bf16*)(ws + off); off += (size_t)NPAD * HID;                          // bf16 [2][NPAD][128]
  float* qi   = ws + off; off += (size_t)2 * NPAD * HEADS;
  float* kj   = ws + off; off += (size_t)2 * NPAD * HEADS;
  unsigned* menc = (unsigned*)(ws + off); off += (size_t)NPAD * HEADS;   // contiguous zero region:
  float* ssum = ws + off; off += (size_t)NPAD * HEADS;                   // menc|ssum|agg
  float* agg  = ws + off; off += (size_t)NPAD * HID;
  unsigned short* aggb = (unsigned short*)(ws + off); off += (size_t)NPAD * HID / 2;
  float* ae   = ws + off; off += (size_t)E_EDGES * HEADS;
  int* srcA = (int*)(ws + off); off += E_EDGES;
  int* dstA = (int*)(ws + off); off += E_EDGES;
  int* etA  = (int*)(ws + off); off += E_EDGES;
  unsigned short* Wbt = (unsigned short*)(ws + off); off += (size_t)2 * 2 * HID * HID / 2; // bf16 [l][r][o][i]
  unsigned short* pWTb = (unsigned short*)(ws + off); off += (size_t)HID * HID / 2;
  float* Qf  = ws + off; off += 2 * HID * HEADS;
  float* Kf  = ws + off; off += 2 * HID * HEADS;
  float* cbf = ws + off; off += 2 * HID;
  float* pbf = ws + off; off += 2 * HID;
  float* pWf = ws + off; off += (size_t)2 * HID * HID;
  float* bo  = ws + off; off += HID;

  detect_kernel<<<1, 256, 0, stream>>>((const unsigned short*)x, eidx, flags);
  cvt_idx_kernel<<<(E_EDGES + 255) / 256, 256, 0, stream>>>(eidx, etype, srcA, dstA, etA, flags);
  cvt_xb_kernel<<<(N_NODES * HID + 255) / 256, 256, 0, stream>>>(x, hb, N_NODES * HID, flags);

  const int iW[2] = {3, 9}, iQ[2] = {4, 10}, iK[2] = {5, 11}, icb[2] = {6, 12}, ipW[2] = {7, 13}, ipb[2] = {8, 14};
  for (int l = 0; l < 2; ++l) {
    cvt_wt_kernel<<<(2 * HID * HID + 255) / 256, 256, 0, stream>>>(d_in[iW[l]], Wbt + (size_t)l * 2 * HID * HID, flags);
    cvt_f_kernel<<<(HID * HEADS + 255) / 256, 256, 0, stream>>>(d_in[iQ[l]], Qf + l * HID * HEADS, HID * HEADS, flags);
    cvt_f_kernel<<<(HID * HEADS + 255) / 256, 256, 0, stream>>>(d_in[iK[l]], Kf + l * HID * HEADS, HID * HEADS, flags);
    cvt_f_kernel<<<1, 256, 0, stream>>>(d_in[icb[l]], cbf + l * HID, HID, flags);
    cvt_f_kernel<<<1, 256, 0, stream>>>(d_in[ipb[l]], pbf + l * HID, HID, flags);
    cvt_f_kernel<<<(HID * HID + 255) / 256, 256, 0, stream>>>(d_in[ipW[l]], pWf + (size_t)l * HID * HID, HID * HID, flags);
  }

  const int zeroN = NPAD * (HEADS + HEADS + HID);   // menc+ssum+agg contiguous
  const int MB = (NPAD + 255) / 256;                 // 196 row-blocks
  for (int l = 0; l < 2; ++l) {
    gemm_xw_mfma<<<dim3(4, MB), 256, 0, stream>>>(hb, Wbt + (size_t)l * 2 * HID * HID, xw);
    qk_kernel<<<(2 * NPAD + 3) / 4, 256, 0, stream>>>(xw, Qf + l * HID * HEADS, Kf + l * HID * HEADS, qi, kj);
    zero_kernel<<<(zeroN + 255) / 256, 256, 0, stream>>>((float*)menc, zeroN);
    edge_alpha_max_kernel<<<(E_EDGES + 255) / 256, 256, 0, stream>>>(srcA, dstA, etA, qi, kj, ae, menc);
    edge_exp_sum_kernel<<<(E_EDGES + 255) / 256, 256, 0, stream>>>(dstA, ae, menc, ssum);
    edge_agg_kernel<<<(E_EDGES + 1) / 2, 256, 0, stream>>>(srcA, dstA, etA, ae, ssum, xw, agg);
    prep_proj_kernel<<<1, 128, 0, stream>>>(pWf + (size_t)l * HID * HID, cbf + l * HID, pbf + l * HID, pWTb, bo);
    cast_aggb_kernel<<<(NPAD * HID + 255) / 256, 256, 0, stream>>>(agg, aggb);
    proj_mfma<<<dim3(2, MB), 256, 0, stream>>>(aggb, pWTb, bo, hb, (l == 1) ? d_out : nullptr, flags);
  }
}

// Round 4
// 524.503 us; speedup vs baseline: 4.1769x; 2.6129x over previous
//
#include <hip/hip_runtime.h>
#include <hip/hip_bf16.h>

typedef __hip_bfloat16 bf16;
typedef short s16x8 __attribute__((ext_vector_type(8)));
typedef float f32x4 __attribute__((ext_vector_type(4)));

#define N_NODES 50000
#define NPAD    50048          // multiple of 64
#define E_EDGES 600000
#define HID     128
#define HEADS   4
#define SCAN_B  196            // ceil(NPAD/256)

// ---- float -> bf16 bits (RNE), finite inputs only ----
__device__ __forceinline__ unsigned short f2bf_bits(float f) {
  unsigned u = __float_as_uint(f);
  u += 0x7fffu + ((u >> 16) & 1u);
  return (unsigned short)(u >> 16);
}
__device__ __forceinline__ float bf2f(unsigned short b) {
  return __uint_as_float(((unsigned)b) << 16);
}

// ---- runtime dtype detection ----
// flags[0]=1 -> float tensors are fp32 (else bf16). flags[1]=1 -> indices are int64.
__global__ __launch_bounds__(256) void detect_kernel(const unsigned short* __restrict__ xb,
                                                     const int* __restrict__ ei,
                                                     int* __restrict__ flags) {
  int t = threadIdx.x;
  __shared__ int cnt[2];
  if (t < 2) cnt[t] = 0;
  __syncthreads();
  unsigned short v = xb[2 * t];
  int ex = (v >> 7) & 0xFF;
  if (ex < 119 || ex > 135) atomicAdd(&cnt[0], 1);
  if (ei[2 * t + 1] != 0) atomicAdd(&cnt[1], 1);
  __syncthreads();
  if (t == 0) {
    flags[0] = (cnt[0] > 64) ? 1 : 0;
    flags[1] = (cnt[1] == 0) ? 1 : 0;
  }
}

// ---- index conversion: dstA[e], pk[e] = src | (r<<16) ----
__global__ __launch_bounds__(256) void cvt_idx_kernel(const int* __restrict__ eidx,
                                                      const int* __restrict__ etype,
                                                      int* __restrict__ dstA, int* __restrict__ pk,
                                                      const int* __restrict__ flags) {
  int e = blockIdx.x * 256 + threadIdx.x;
  if (e >= E_EDGES) return;
  int s, d, r;
  if (flags[1]) {
    const long long* e64 = (const long long*)eidx;
    const long long* t64 = (const long long*)etype;
    s = (int)e64[e]; d = (int)e64[E_EDGES + e]; r = (int)t64[e];
  } else {
    s = eidx[e]; d = eidx[E_EDGES + e]; r = etype[e];
  }
  dstA[e] = d;
  pk[e] = s | (r << 16);
}

// ---- float-tensor -> bf16 bits ----
__global__ __launch_bounds__(256) void cvt_xb_kernel(const void* __restrict__ src,
                                                     unsigned short* __restrict__ dst, int n,
                                                     const int* __restrict__ flags) {
  int i = blockIdx.x * 256 + threadIdx.x;
  if (i >= n) return;
  if (flags[0]) dst[i] = f2bf_bits(((const float*)src)[i]);
  else          dst[i] = ((const unsigned short*)src)[i];
}

// ---- W (both layers) [128(in)][128(out)] -> bf16 N-major [l][r][o][i] ----
__global__ __launch_bounds__(256) void cvt_wt_kernel(const void* __restrict__ src0,
                                                     const void* __restrict__ src1,
                                                     unsigned short* __restrict__ dst,
                                                     const int* __restrict__ flags) {
  int idx = blockIdx.x * 256 + threadIdx.x;
  if (idx >= 2 * 2 * HID * HID) return;
  int l = idx >> 15, rem = idx & 32767;
  int r = rem >> 14, i = (rem >> 7) & 127, o = rem & 127;
  const void* src = l ? src1 : src0;
  unsigned short b;
  if (flags[0]) b = f2bf_bits(((const float*)src)[rem]);
  else          b = ((const unsigned short*)src)[rem];
  dst[(size_t)l * 2 * HID * HID + ((size_t)r * HID + o) * HID + i] = b;
}

// ---- small params (Q,K,cb,pb for both layers) -> fp32 block ----
struct P8 { const void* src[8]; int dstoff[8]; int n[8]; };
__global__ __launch_bounds__(256) void cvt_params_kernel(P8 tab, float* __restrict__ base,
                                                         const int* __restrict__ flags) {
  const int f = flags[0];
  for (int k = 0; k < 8; ++k) {
    int n = tab.n[k];
    for (int i = blockIdx.x * 256 + threadIdx.x; i < n; i += gridDim.x * 256) {
      float v = f ? ((const float*)tab.src[k])[i] : bf2f(((const unsigned short*)tab.src[k])[i]);
      base[tab.dstoff[k] + i] = v;
    }
  }
}

__global__ __launch_bounds__(256) void zero_int_kernel(int* __restrict__ p, int n) {
  int i = blockIdx.x * 256 + threadIdx.x;
  if (i < n) p[i] = 0;
}

// ---- counting sort: histogram / scan / scatter ----
__global__ __launch_bounds__(256) void hist_kernel(const int* __restrict__ dstA,
                                                   int* __restrict__ deg) {
  int e = blockIdx.x * 256 + threadIdx.x;
  if (e < E_EDGES) atomicAdd(&deg[dstA[e]], 1);
}

__global__ __launch_bounds__(256) void scan1_kernel(const int* __restrict__ deg,
                                                    int* __restrict__ excl,
                                                    int* __restrict__ bsum) {
  __shared__ int sm[256];
  int t = threadIdx.x, i = blockIdx.x * 256 + t;
  int v = (i < NPAD) ? deg[i] : 0;
  sm[t] = v;
  __syncthreads();
#pragma unroll
  for (int off = 1; off < 256; off <<= 1) {
    int add = (t >= off) ? sm[t - off] : 0;
    __syncthreads();
    sm[t] += add;
    __syncthreads();
  }
  if (i < NPAD) excl[i] = sm[t] - v;
  if (t == 255) bsum[blockIdx.x] = sm[255];
}

__global__ __launch_bounds__(256) void scan2_kernel(int* __restrict__ bsum,
                                                    int* __restrict__ bscan) {
  __shared__ int sm[256];
  int t = threadIdx.x;
  int v = (t < SCAN_B) ? bsum[t] : 0;
  sm[t] = v;
  __syncthreads();
#pragma unroll
  for (int off = 1; off < 256; off <<= 1) {
    int add = (t >= off) ? sm[t - off] : 0;
    __syncthreads();
    sm[t] += add;
    __syncthreads();
  }
  bscan[t] = sm[t] - v;   // exclusive
}

__global__ __launch_bounds__(256) void scan3_kernel(const int* __restrict__ excl,
                                                    const int* __restrict__ bscan,
                                                    int* __restrict__ rowstart) {
  int i = blockIdx.x * 256 + threadIdx.x;
  if (i < NPAD) rowstart[i] = excl[i] + bscan[blockIdx.x];
  if (i == 0) rowstart[NPAD] = E_EDGES;
}

__global__ __launch_bounds__(256) void scatter_kernel(const int* __restrict__ dstA,
                                                      const int* __restrict__ pk,
                                                      const int* __restrict__ rowstart,
                                                      int* __restrict__ cnt,
                                                      int* __restrict__ eord) {
  int e = blockIdx.x * 256 + threadIdx.x;
  if (e >= E_EDGES) return;
  int d = dstA[e];
  int pos = rowstart[d] + atomicAdd(&cnt[d], 1);
  eord[pos] = pk[e];
}

// ================= MFMA GEMM core: one wave -> 64 rows x 64 cols, K=128 ======
__device__ __forceinline__ void wave_gemm64(const unsigned short* __restrict__ Ab, int row0,
                                            const unsigned short* __restrict__ Bt, int colb,
                                            int lane, f32x4 acc[4][4]) {
  const int lm = lane & 15, q = lane >> 4;
#pragma unroll
  for (int kc = 0; kc < 4; ++kc) {
    const int ko = kc * 32 + q * 8;
    s16x8 af[4], bfr[4];
#pragma unroll
    for (int rt = 0; rt < 4; ++rt)
      af[rt] = *(const s16x8*)(Ab + (size_t)(row0 + rt * 16 + lm) * HID + ko);
#pragma unroll
    for (int ct = 0; ct < 4; ++ct)
      bfr[ct] = *(const s16x8*)(Bt + (size_t)(colb + ct * 16 + lm) * HID + ko);
#pragma unroll
    for (int rt = 0; rt < 4; ++rt)
#pragma unroll
      for (int ct = 0; ct < 4; ++ct)
        acc[rt][ct] = __builtin_amdgcn_mfma_f32_16x16x32_bf16(af[rt], bfr[ct], acc[rt][ct], 0, 0, 0);
  }
}

// ---- xw[r,n,:] = h[n,:] @ W[r]  (bf16 mfma) ----
__global__ __launch_bounds__(256) void gemm_xw_mfma(const unsigned short* __restrict__ hb,
                                                    const unsigned short* __restrict__ Wbt,
                                                    unsigned short* __restrict__ xw) {
  const int wave = threadIdx.x >> 6, lane = threadIdx.x & 63;
  const int row0 = blockIdx.y * 256 + wave * 64;
  if (row0 >= NPAD) return;
  const int bn = blockIdx.x;
  const int r = bn >> 1, colb = (bn & 1) * 64;
  f32x4 acc[4][4];
#pragma unroll
  for (int a = 0; a < 4; ++a)
#pragma unroll
    for (int b = 0; b < 4; ++b) { f32x4 z = {0.f, 0.f, 0.f, 0.f}; acc[a][b] = z; }
  wave_gemm64(hb, row0, Wbt + (size_t)r * HID * HID, colb, lane, acc);
  const int lm = lane & 15, q = lane >> 4;
#pragma unroll
  for (int rt = 0; rt < 4; ++rt)
#pragma unroll
    for (int i = 0; i < 4; ++i) {
      int row = row0 + rt * 16 + q * 4 + i;
      if (row < N_NODES) {
#pragma unroll
        for (int ct = 0; ct < 4; ++ct) {
          int o = colb + ct * 16 + lm;
          xw[((size_t)r * NPAD + row) * HID + o] = f2bf_bits(acc[rt][ct][i]);
        }
      }
    }
}

// ---- out[n,o] = elu( agg[n,:] @ pW.T + bo ), dual-dtype output ----
__global__ __launch_bounds__(256) void proj_mfma(const unsigned short* __restrict__ aggb,
                                                 const unsigned short* __restrict__ pWTb,
                                                 const float* __restrict__ bo,
                                                 unsigned short* __restrict__ hbout,
                                                 void* __restrict__ dout,
                                                 const int* __restrict__ flags) {
  const int wave = threadIdx.x >> 6, lane = threadIdx.x & 63;
  const int row0 = blockIdx.y * 256 + wave * 64;
  if (row0 >= NPAD) return;
  const int colb = blockIdx.x * 64;
  f32x4 acc[4][4];
#pragma unroll
  for (int a = 0; a < 4; ++a)
#pragma unroll
    for (int b = 0; b < 4; ++b) { f32x4 z = {0.f, 0.f, 0.f, 0.f}; acc[a][b] = z; }
  wave_gemm64(aggb, row0, pWTb, colb, lane, acc);
  const int lm = lane & 15, q = lane >> 4;
  const int f32out = flags[0];
#pragma unroll
  for (int rt = 0; rt < 4; ++rt)
#pragma unroll
    for (int i = 0; i < 4; ++i) {
      int row = row0 + rt * 16 + q * 4 + i;
      if (row < N_NODES) {
#pragma unroll
        for (int ct = 0; ct < 4; ++ct) {
          int o = colb + ct * 16 + lm;
          float v = acc[rt][ct][i] + bo[o];
          v = v > 0.f ? v : expm1f(v);       // ELU
          size_t idx = (size_t)row * HID + o;
          if (dout) {
            if (f32out) ((float*)dout)[idx] = v;
            else        ((unsigned short*)dout)[idx] = f2bf_bits(v);
          } else {
            hbout[idx] = f2bf_bits(v);
          }
        }
      }
    }
}

// ---- qi[r,n,h] = xw[r,n,:]·Q[:,h]; kj likewise with K.  One wave per (r,n). ----
__global__ __launch_bounds__(256) void qk_kernel(const unsigned short* __restrict__ xw,
                                                 const float* __restrict__ Qf,
                                                 const float* __restrict__ Kf,
                                                 float* __restrict__ qi,
                                                 float* __restrict__ kj) {
  int w    = blockIdx.x * 4 + (threadIdx.x >> 6);
  int lane = threadIdx.x & 63;
  if (w >= 2 * NPAD) return;
  const unsigned short* row = xw + (size_t)w * HID;
  float x0 = bf2f(row[lane]);
  float x1 = bf2f(row[lane + 64]);
  float pq[HEADS], pk4[HEADS];
#pragma unroll
  for (int hh = 0; hh < HEADS; ++hh) {
    pq[hh] = x0 * Qf[lane * HEADS + hh] + x1 * Qf[(lane + 64) * HEADS + hh];
    pk4[hh] = x0 * Kf[lane * HEADS + hh] + x1 * Kf[(lane + 64) * HEADS + hh];
  }
#pragma unroll
  for (int off = 32; off > 0; off >>= 1) {
#pragma unroll
    for (int hh = 0; hh < HEADS; ++hh) {
      pq[hh] += __shfl_down(pq[hh], off);
      pk4[hh] += __shfl_down(pk4[hh], off);
    }
  }
  if (lane == 0) {
#pragma unroll
    for (int hh = 0; hh < HEADS; ++hh) {
      qi[(size_t)w * HEADS + hh] = pq[hh];
      kj[(size_t)w * HEADS + hh] = pk4[hh];
    }
  }
}

__device__ __forceinline__ float lrelu(float v) { return v >= 0.f ? v : 0.2f * v; }

// ---- fused per-dst-node: alpha -> segment softmax -> weighted aggregate ----
// One wave per node. Writes aggb row (bf16) once.
__global__ __launch_bounds__(256) void edge_fused_kernel(
    const int* __restrict__ rowstart, const int* __restrict__ eord,
    const float4* __restrict__ qi4, const float4* __restrict__ kj4,
    const unsigned short* __restrict__ xw, unsigned short* __restrict__ aggb) {
  const int wave = threadIdx.x >> 6, lane = threadIdx.x & 63;
  const int n = blockIdx.x * 4 + wave;
  if (n >= N_NODES) return;
  unsigned* outp = (unsigned*)(aggb + (size_t)n * HID) + lane;   // 2 channels/lane
  const int start = rowstart[n], end = rowstart[n + 1];
  const int deg = end - start;
  if (deg == 0) { *outp = 0u; return; }
  const int hh = lane >> 4;                 // head of my channel pair
  const float4 q0 = qi4[n], q1 = qi4[NPAD + n];
  float2 acc = {0.f, 0.f};
  float ssel;

  if (deg <= 64) {
    // ---- fast path: lane <-> edge ----
    int p = 0;
    float a0 = -1e30f, a1 = -1e30f, a2 = -1e30f, a3 = -1e30f;
    const bool act = lane < deg;
    if (act) {
      p = eord[start + lane];
      int s = p & 0xffff, r = p >> 16;
      float4 k4 = kj4[(size_t)r * NPAD + s];
      float4 q4 = r ? q1 : q0;
      a0 = lrelu(q4.x + k4.x); a1 = lrelu(q4.y + k4.y);
      a2 = lrelu(q4.z + k4.z); a3 = lrelu(q4.w + k4.w);
    }
    float m0 = a0, m1 = a1, m2 = a2, m3 = a3;
#pragma unroll
    for (int off = 32; off > 0; off >>= 1) {
      m0 = fmaxf(m0, __shfl_xor(m0, off));
      m1 = fmaxf(m1, __shfl_xor(m1, off));
      m2 = fmaxf(m2, __shfl_xor(m2, off));
      m3 = fmaxf(m3, __shfl_xor(m3, off));
    }
    float w0 = act ? __expf(a0 - m0) : 0.f;
    float w1 = act ? __expf(a1 - m1) : 0.f;
    float w2 = act ? __expf(a2 - m2) : 0.f;
    float w3 = act ? __expf(a3 - m3) : 0.f;
    float s0 = w0, s1 = w1, s2 = w2, s3 = w3;
#pragma unroll
    for (int off = 32; off > 0; off >>= 1) {
      s0 += __shfl_xor(s0, off);
      s1 += __shfl_xor(s1, off);
      s2 += __shfl_xor(s2, off);
      s3 += __shfl_xor(s3, off);
    }
    ssel = hh == 0 ? s0 : hh == 1 ? s1 : hh == 2 ? s2 : s3;
    for (int e = 0; e < deg; ++e) {
      float e0 = __shfl(w0, e), e1 = __shfl(w1, e), e2 = __shfl(w2, e), e3 = __shfl(w3, e);
      float we = hh == 0 ? e0 : hh == 1 ? e1 : hh == 2 ? e2 : e3;
      int pe = __shfl(p, e);
      int s = pe & 0xffff, r = pe >> 16;
      unsigned v = *(const unsigned*)(xw + (((size_t)r * NPAD + s) << 7) + (lane << 1));
      acc.x += bf2f((unsigned short)(v & 0xffffu)) * we;
      acc.y += bf2f((unsigned short)(v >> 16)) * we;
    }
  } else {
    // ---- generic fallback (deg > 64): wave-uniform serial, rare ----
    float4 m = make_float4(-1e30f, -1e30f, -1e30f, -1e30f);
    for (int e = start; e < end; ++e) {
      int pe = eord[e];
      int s = pe & 0xffff, r = pe >> 16;
      float4 k4 = kj4[(size_t)r * NPAD + s];
      float4 q4 = r ? q1 : q0;
      m.x = fmaxf(m.x, lrelu(q4.x + k4.x)); m.y = fmaxf(m.y, lrelu(q4.y + k4.y));
      m.z = fmaxf(m.z, lrelu(q4.z + k4.z)); m.w = fmaxf(m.w, lrelu(q4.w + k4.w));
    }
    float4 sv = make_float4(0.f, 0.f, 0.f, 0.f);
    for (int e = start; e < end; ++e) {
      int pe = eord[e];
      int s = pe & 0xffff, r = pe >> 16;
      float4 k4 = kj4[(size_t)r * NPAD + s];
      float4 q4 = r ? q1 : q0;
      float w0 = __expf(lrelu(q4.x + k4.x) - m.x);
      float w1 = __expf(lrelu(q4.y + k4.y) - m.y);
      float w2 = __expf(lrelu(q4.z + k4.z) - m.z);
      float w3 = __expf(lrelu(q4.w + k4.w) - m.w);
      sv.x += w0; sv.y += w1; sv.z += w2; sv.w += w3;
      float we = hh == 0 ? w0 : hh == 1 ? w1 : hh == 2 ? w2 : w3;
      unsigned v = *(const unsigned*)(xw + (((size_t)r * NPAD + s) << 7) + (lane << 1));
      acc.x += bf2f((unsigned short)(v & 0xffffu)) * we;
      acc.y += bf2f((unsigned short)(v >> 16)) * we;
    }
    ssel = hh == 0 ? sv.x : hh == 1 ? sv.y : hh == 2 ? sv.z : sv.w;
  }
  float inv = 1.f / (ssel + 1e-16f);
  unsigned outv = (unsigned)f2bf_bits(acc.x * inv) | ((unsigned)f2bf_bits(acc.y * inv) << 16);
  *outp = outv;
}

// ---- per-output-channel: pWTb[o][i] = bf16(pW[o][i]); bo[o] = pb[o] + cb·pW[o,:] ----
__global__ __launch_bounds__(64) void prep_proj_kernel(const void* __restrict__ pWraw,
                                                       const float* __restrict__ cb,
                                                       const float* __restrict__ pb,
                                                       unsigned short* __restrict__ pWTb,
                                                       float* __restrict__ bo,
                                                       const int* __restrict__ flags) {
  int o = blockIdx.x, t = threadIdx.x;
  const int f = flags[0];
  float part = 0.f;
#pragma unroll
  for (int i = t; i < HID; i += 64) {
    float w = f ? ((const float*)pWraw)[o * HID + i] : bf2f(((const unsigned short*)pWraw)[o * HID + i]);
    pWTb[o * HID + i] = f2bf_bits(w);
    part += cb[i] * w;
  }
#pragma unroll
  for (int off = 32; off > 0; off >>= 1) part += __shfl_xor(part, off);
  if (t == 0) bo[o] = pb[o] + part;
}

extern "C" void kernel_launch(void* const* d_in, const int* in_sizes, int n_in,
                              void* d_out, int out_size, void* d_ws, size_t ws_size,
                              hipStream_t stream) {
  const void* x     = d_in[0];
  const int*  eidx  = (const int*)d_in[1];
  const int*  etype = (const int*)d_in[2];
  const int iW[2] = {3, 9}, iQ[2] = {4, 10}, iK[2] = {5, 11}, icb[2] = {6, 12}, ipW[2] = {7, 13}, ipb[2] = {8, 14};

  float* ws = (float*)d_ws;
  size_t off = 0;
  int*   flags = (int*)(ws + off); off += 16;
  unsigned short* hb   = (unsigned short*)(ws + off); off += (size_t)NPAD * HID / 2;     // bf16 [NPAD][128]
  unsigned short* xw   = (unsigned short*)(ws + off); off += (size_t)NPAD * HID;         // bf16 [2][NPAD][128]
  float* qi   = ws + off; off += (size_t)2 * NPAD * HEADS;
  float* kj   = ws + off; off += (size_t)2 * NPAD * HEADS;
  unsigned short* aggb = (unsigned short*)(ws + off); off += (size_t)NPAD * HID / 2;     // bf16 [NPAD][128]
  int* dstA = (int*)(ws + off); off += E_EDGES;
  int* pk   = (int*)(ws + off); off += E_EDGES;
  int* eord = (int*)(ws + off); off += E_EDGES;
  int* deg  = (int*)(ws + off); off += NPAD;        // deg|cnt contiguous for one zero pass
  int* cnt  = (int*)(ws + off); off += NPAD;
  int* excl = (int*)(ws + off); off += NPAD;
  int* rowstart = (int*)(ws + off); off += NPAD + 16;
  int* bsum  = (int*)(ws + off); off += 256;
  int* bscan = (int*)(ws + off); off += 256;
  unsigned short* Wbt  = (unsigned short*)(ws + off); off += (size_t)2 * 2 * HID * HID / 2;
  unsigned short* pWTb = (unsigned short*)(ws + off); off += (size_t)HID * HID / 2;
  float* Qf  = ws + off; off += 2 * HID * HEADS;
  float* Kf  = ws + off; off += 2 * HID * HEADS;
  float* cbf = ws + off; off += 2 * HID;
  float* pbf = ws + off; off += 2 * HID;
  float* bo  = ws + off; off += HID;

  // ---- detect + convert ----
  detect_kernel<<<1, 256, 0, stream>>>((const unsigned short*)x, eidx, flags);
  cvt_idx_kernel<<<(E_EDGES + 255) / 256, 256, 0, stream>>>(eidx, etype, dstA, pk, flags);
  cvt_xb_kernel<<<(N_NODES * HID + 255) / 256, 256, 0, stream>>>(x, hb, N_NODES * HID, flags);
  cvt_wt_kernel<<<(2 * 2 * HID * HID + 255) / 256, 256, 0, stream>>>(d_in[iW[0]], d_in[iW[1]], Wbt, flags);
  {
    P8 tab;
    float* base = ws;  // offsets relative to ws start
    for (int l = 0; l < 2; ++l) {
      tab.src[l * 4 + 0] = d_in[iQ[l]];  tab.dstoff[l * 4 + 0] = (int)(Qf - base) + l * HID * HEADS;  tab.n[l * 4 + 0] = HID * HEADS;
      tab.src[l * 4 + 1] = d_in[iK[l]];  tab.dstoff[l * 4 + 1] = (int)(Kf - base) + l * HID * HEADS;  tab.n[l * 4 + 1] = HID * HEADS;
      tab.src[l * 4 + 2] = d_in[icb[l]]; tab.dstoff[l * 4 + 2] = (int)(cbf - base) + l * HID;         tab.n[l * 4 + 2] = HID;
      tab.src[l * 4 + 3] = d_in[ipb[l]]; tab.dstoff[l * 4 + 3] = (int)(pbf - base) + l * HID;         tab.n[l * 4 + 3] = HID;
    }
    cvt_params_kernel<<<2, 256, 0, stream>>>(tab, base, flags);
  }

  // ---- counting sort by dst ----
  zero_int_kernel<<<(2 * NPAD + 255) / 256, 256, 0, stream>>>(deg, 2 * NPAD);   // deg + cnt
  hist_kernel<<<(E_EDGES + 255) / 256, 256, 0, stream>>>(dstA, deg);
  scan1_kernel<<<SCAN_B, 256, 0, stream>>>(deg, excl, bsum);
  scan2_kernel<<<1, 256, 0, stream>>>(bsum, bscan);
  scan3_kernel<<<SCAN_B, 256, 0, stream>>>(excl, bscan, rowstart);
  scatter_kernel<<<(E_EDGES + 255) / 256, 256, 0, stream>>>(dstA, pk, rowstart, cnt, eord);

  const int MB = (NPAD + 255) / 256;
  for (int l = 0; l < 2; ++l) {
    gemm_xw_mfma<<<dim3(4, MB), 256, 0, stream>>>(hb, Wbt + (size_t)l * 2 * HID * HID, xw);
    qk_kernel<<<(2 * NPAD + 3) / 4, 256, 0, stream>>>(xw, Qf + l * HID * HEADS, Kf + l * HID * HEADS, qi, kj);
    edge_fused_kernel<<<(N_NODES + 3) / 4, 256, 0, stream>>>(rowstart, eord, (const float4*)qi, (const float4*)kj, xw, aggb);
    prep_proj_kernel<<<HID, 64, 0, stream>>>(d_in[ipW[l]], cbf + l * HID, pbf + l * HID, pWTb, bo, flags);
    proj_mfma<<<dim3(2, MB), 256, 0, stream>>>(aggb, pWTb, bo, hb, (l == 1) ? d_out : nullptr, flags);
  }
}

// Round 5
// 478.365 us; speedup vs baseline: 4.5798x; 1.0965x over previous
//
#include <hip/hip_runtime.h>
#include <hip/hip_bf16.h>

typedef __hip_bfloat16 bf16;
typedef short s16x8 __attribute__((ext_vector_type(8)));
typedef float f32x4 __attribute__((ext_vector_type(4)));

#define N_NODES 50000
#define NPAD    50048          // multiple of 64
#define E_EDGES 600000
#define HID     128
#define HEADS   4
#define SCAN_B  196            // ceil(NPAD/256)

// ---- float -> bf16 bits (RNE), finite inputs only ----
__device__ __forceinline__ unsigned short f2bf_bits(float f) {
  unsigned u = __float_as_uint(f);
  u += 0x7fffu + ((u >> 16) & 1u);
  return (unsigned short)(u >> 16);
}
__device__ __forceinline__ float bf2f(unsigned short b) {
  return __uint_as_float(((unsigned)b) << 16);
}
// packed-dword bf16 pair -> floats (1 op each)
__device__ __forceinline__ float lo_f(unsigned v) { return __uint_as_float(v << 16); }
__device__ __forceinline__ float hi_f(unsigned v) { return __uint_as_float(v & 0xffff0000u); }

__device__ __forceinline__ float lrelu(float v) { return v >= 0.f ? v : 0.2f * v; }

// ---- runtime dtype detection ----
// flags[0]=1 -> float tensors are fp32 (else bf16). flags[1]=1 -> indices are int64.
__global__ __launch_bounds__(256) void detect_kernel(const unsigned short* __restrict__ xb,
                                                     const int* __restrict__ ei,
                                                     int* __restrict__ flags) {
  int t = threadIdx.x;
  __shared__ int cnt[2];
  if (t < 2) cnt[t] = 0;
  __syncthreads();
  unsigned short v = xb[2 * t];
  int ex = (v >> 7) & 0xFF;
  if (ex < 119 || ex > 135) atomicAdd(&cnt[0], 1);
  if (ei[2 * t + 1] != 0) atomicAdd(&cnt[1], 1);
  __syncthreads();
  if (t == 0) {
    flags[0] = (cnt[0] > 64) ? 1 : 0;
    flags[1] = (cnt[1] == 0) ? 1 : 0;
  }
}

__global__ __launch_bounds__(256) void zero_int_kernel(int* __restrict__ p, int n) {
  int i = blockIdx.x * 256 + threadIdx.x;
  if (i < n) p[i] = 0;
}

// ---- index conversion + degree histogram: dstA[e], pk[e] = src | (r<<16) ----
__global__ __launch_bounds__(256) void cvt_idx_hist_kernel(const int* __restrict__ eidx,
                                                           const int* __restrict__ etype,
                                                           int* __restrict__ dstA, int* __restrict__ pk,
                                                           int* __restrict__ deg,
                                                           const int* __restrict__ flags) {
  int e = blockIdx.x * 256 + threadIdx.x;
  if (e >= E_EDGES) return;
  int s, d, r;
  if (flags[1]) {
    const long long* e64 = (const long long*)eidx;
    const long long* t64 = (const long long*)etype;
    s = (int)e64[e]; d = (int)e64[E_EDGES + e]; r = (int)t64[e];
  } else {
    s = eidx[e]; d = eidx[E_EDGES + e]; r = etype[e];
  }
  dstA[e] = d;
  pk[e] = s | (r << 16);
  atomicAdd(&deg[d], 1);
}

// ---- float-tensor -> bf16 bits ----
__global__ __launch_bounds__(256) void cvt_xb_kernel(const void* __restrict__ src,
                                                     unsigned short* __restrict__ dst, int n,
                                                     const int* __restrict__ flags) {
  int i = blockIdx.x * 256 + threadIdx.x;
  if (i >= n) return;
  if (flags[0]) dst[i] = f2bf_bits(((const float*)src)[i]);
  else          dst[i] = ((const unsigned short*)src)[i];
}

// ---- W (both layers) [128(in)][128(out)] -> bf16 N-major [l][r][o][i] ----
__global__ __launch_bounds__(256) void cvt_wt_kernel(const void* __restrict__ src0,
                                                     const void* __restrict__ src1,
                                                     unsigned short* __restrict__ dst,
                                                     const int* __restrict__ flags) {
  int idx = blockIdx.x * 256 + threadIdx.x;
  if (idx >= 2 * 2 * HID * HID) return;
  int l = idx >> 15, rem = idx & 32767;
  int r = rem >> 14, i = (rem >> 7) & 127, o = rem & 127;
  const void* src = l ? src1 : src0;
  unsigned short b;
  if (flags[0]) b = f2bf_bits(((const float*)src)[rem]);
  else          b = ((const unsigned short*)src)[rem];
  dst[(size_t)l * 2 * HID * HID + ((size_t)r * HID + o) * HID + i] = b;
}

// ---- small params (Q,K,cb,pb for both layers) -> fp32 block ----
struct P8 { const void* src[8]; int dstoff[8]; int n[8]; };
__global__ __launch_bounds__(256) void cvt_params_kernel(P8 tab, float* __restrict__ base,
                                                         const int* __restrict__ flags) {
  const int f = flags[0];
  for (int k = 0; k < 8; ++k) {
    int n = tab.n[k];
    for (int i = blockIdx.x * 256 + threadIdx.x; i < n; i += gridDim.x * 256) {
      float v = f ? ((const float*)tab.src[k])[i] : bf2f(((const unsigned short*)tab.src[k])[i]);
      base[tab.dstoff[k] + i] = v;
    }
  }
}

// ---- scan stage 1: per-256-block inclusive scan ----
__global__ __launch_bounds__(256) void scan1_kernel(const int* __restrict__ deg,
                                                    int* __restrict__ excl,
                                                    int* __restrict__ bsum) {
  __shared__ int sm[256];
  int t = threadIdx.x, i = blockIdx.x * 256 + t;
  int v = (i < NPAD) ? deg[i] : 0;
  sm[t] = v;
  __syncthreads();
#pragma unroll
  for (int off = 1; off < 256; off <<= 1) {
    int add = (t >= off) ? sm[t - off] : 0;
    __syncthreads();
    sm[t] += add;
    __syncthreads();
  }
  if (i < NPAD) excl[i] = sm[t] - v;
  if (t == 255) bsum[blockIdx.x] = sm[255];
}

// ---- scan stages 2+3 fused: each block redundantly scans bsum, adds prefix ----
__global__ __launch_bounds__(256) void scan23_kernel(const int* __restrict__ excl,
                                                     const int* __restrict__ bsum,
                                                     int* __restrict__ rowstart) {
  __shared__ int sm[256];
  int t = threadIdx.x;
  int v = (t < SCAN_B) ? bsum[t] : 0;
  sm[t] = v;
  __syncthreads();
#pragma unroll
  for (int off = 1; off < 256; off <<= 1) {
    int add = (t >= off) ? sm[t - off] : 0;
    __syncthreads();
    sm[t] += add;
    __syncthreads();
  }
  int bpre = (blockIdx.x > 0) ? sm[blockIdx.x - 1] : 0;   // exclusive block prefix
  int i = blockIdx.x * 256 + t;
  if (i < NPAD) rowstart[i] = excl[i] + bpre;
  if (i == 0) rowstart[NPAD] = E_EDGES;
}

__global__ __launch_bounds__(256) void scatter_kernel(const int* __restrict__ dstA,
                                                      const int* __restrict__ pk,
                                                      const int* __restrict__ rowstart,
                                                      int* __restrict__ cnt,
                                                      int* __restrict__ eord) {
  int e = blockIdx.x * 256 + threadIdx.x;
  if (e >= E_EDGES) return;
  int d = dstA[e];
  int pos = rowstart[d] + atomicAdd(&cnt[d], 1);
  eord[pos] = pk[e];
}

// ================= MFMA GEMM core: one wave -> 64 rows x 64 cols, K=128 ======
__device__ __forceinline__ void wave_gemm64(const unsigned short* __restrict__ Ab, int row0,
                                            const unsigned short* __restrict__ Bt, int colb,
                                            int lane, f32x4 acc[4][4]) {
  const int lm = lane & 15, q = lane >> 4;
#pragma unroll
  for (int kc = 0; kc < 4; ++kc) {
    const int ko = kc * 32 + q * 8;
    s16x8 af[4], bfr[4];
#pragma unroll
    for (int rt = 0; rt < 4; ++rt)
      af[rt] = *(const s16x8*)(Ab + (size_t)(row0 + rt * 16 + lm) * HID + ko);
#pragma unroll
    for (int ct = 0; ct < 4; ++ct)
      bfr[ct] = *(const s16x8*)(Bt + (size_t)(colb + ct * 16 + lm) * HID + ko);
#pragma unroll
    for (int rt = 0; rt < 4; ++rt)
#pragma unroll
      for (int ct = 0; ct < 4; ++ct)
        acc[rt][ct] = __builtin_amdgcn_mfma_f32_16x16x32_bf16(af[rt], bfr[ct], acc[rt][ct], 0, 0, 0);
  }
}

// ---- xw[r,n,:] = h[n,:] @ W[r]; block = 4 waves = 4 (r,colpanel) of SAME rows ----
__global__ __launch_bounds__(256) void gemm_xw_mfma(const unsigned short* __restrict__ hb,
                                                    const unsigned short* __restrict__ Wbt,
                                                    unsigned short* __restrict__ xw) {
  const int wave = threadIdx.x >> 6, lane = threadIdx.x & 63;
  const int row0 = blockIdx.x * 64;
  const int r = wave >> 1, colb = (wave & 1) * 64;
  f32x4 acc[4][4];
#pragma unroll
  for (int a = 0; a < 4; ++a)
#pragma unroll
    for (int b = 0; b < 4; ++b) { f32x4 z = {0.f, 0.f, 0.f, 0.f}; acc[a][b] = z; }
  wave_gemm64(hb, row0, Wbt + (size_t)r * HID * HID, colb, lane, acc);
  const int lm = lane & 15, q = lane >> 4;
#pragma unroll
  for (int rt = 0; rt < 4; ++rt)
#pragma unroll
    for (int i = 0; i < 4; ++i) {
      int row = row0 + rt * 16 + q * 4 + i;
      if (row < N_NODES) {
#pragma unroll
        for (int ct = 0; ct < 4; ++ct) {
          int o = colb + ct * 16 + lm;
          xw[((size_t)r * NPAD + row) * HID + o] = f2bf_bits(acc[rt][ct][i]);
        }
      }
    }
}

// ---- out[n,o] = elu( agg[n,:] @ pW.T + bo ); block = 2 waves = 2 col panels ----
__global__ __launch_bounds__(128) void proj_mfma(const unsigned short* __restrict__ aggb,
                                                 const unsigned short* __restrict__ pWTb,
                                                 const float* __restrict__ bo,
                                                 unsigned short* __restrict__ hbout,
                                                 void* __restrict__ dout,
                                                 const int* __restrict__ flags) {
  const int wave = threadIdx.x >> 6, lane = threadIdx.x & 63;
  const int row0 = blockIdx.x * 64;
  const int colb = wave * 64;
  f32x4 acc[4][4];
#pragma unroll
  for (int a = 0; a < 4; ++a)
#pragma unroll
    for (int b = 0; b < 4; ++b) { f32x4 z = {0.f, 0.f, 0.f, 0.f}; acc[a][b] = z; }
  wave_gemm64(aggb, row0, pWTb, colb, lane, acc);
  const int lm = lane & 15, q = lane >> 4;
  const int f32out = flags[0];
#pragma unroll
  for (int rt = 0; rt < 4; ++rt)
#pragma unroll
    for (int i = 0; i < 4; ++i) {
      int row = row0 + rt * 16 + q * 4 + i;
      if (row < N_NODES) {
#pragma unroll
        for (int ct = 0; ct < 4; ++ct) {
          int o = colb + ct * 16 + lm;
          float v = acc[rt][ct][i] + bo[o];
          v = v > 0.f ? v : expm1f(v);       // ELU
          size_t idx = (size_t)row * HID + o;
          if (dout) {
            if (f32out) ((float*)dout)[idx] = v;
            else        ((unsigned short*)dout)[idx] = f2bf_bits(v);
          } else {
            hbout[idx] = f2bf_bits(v);
          }
        }
      }
    }
}

// ---- WQ/WK fold: qtab[l][r][i][h] = sum_j W[l][r][i][j] * Q[l][j][h] ----
__global__ __launch_bounds__(256) void prep_wq_kernel(const unsigned short* __restrict__ Wbt,
                                                      const float* __restrict__ Qf,
                                                      const float* __restrict__ Kf,
                                                      float4* __restrict__ qtab,
                                                      float4* __restrict__ ktab) {
  int idx = blockIdx.x * 256 + threadIdx.x;   // (l,r,i)
  if (idx >= 2 * 2 * HID) return;
  int i = idx & 127, lr = idx >> 7, l = lr >> 1;
  float4 aq = {0.f, 0.f, 0.f, 0.f}, ak = {0.f, 0.f, 0.f, 0.f};
  const unsigned short* Wb = Wbt + (size_t)lr * HID * HID;   // [o=j][i]
  const float* Qp = Qf + l * HID * HEADS;
  const float* Kp = Kf + l * HID * HEADS;
  for (int j = 0; j < HID; ++j) {
    float w = bf2f(Wb[j * HID + i]);
    float4 q4 = *(const float4*)(Qp + j * 4);
    float4 k4 = *(const float4*)(Kp + j * 4);
    aq.x += w * q4.x; aq.y += w * q4.y; aq.z += w * q4.z; aq.w += w * q4.w;
    ak.x += w * k4.x; ak.y += w * k4.y; ak.z += w * k4.z; ak.w += w * k4.w;
  }
  qtab[idx] = aq; ktab[idx] = ak;
}

// ---- qi[r,n,:] / kj[r,n,:] directly from h: one wave per node, both relations ----
__global__ __launch_bounds__(256) void qk_direct_kernel(const unsigned short* __restrict__ hb,
                                                        const float4* __restrict__ qtab,   // [2r][128]
                                                        const float4* __restrict__ ktab,
                                                        float4* __restrict__ qi4,
                                                        float4* __restrict__ kj4) {
  int n = blockIdx.x * 4 + (threadIdx.x >> 6);
  int lane = threadIdx.x & 63;
  if (n >= N_NODES) return;
  unsigned v = *(const unsigned*)(hb + ((size_t)n << 7) + (lane << 1));
  float a0 = lo_f(v), a1 = hi_f(v);
  int c0 = lane << 1, c1 = c0 + 1;
  float4 pq0, pq1, pk0, pk1;
  {
    float4 t0 = qtab[c0], t1 = qtab[c1];
    pq0.x = t0.x * a0 + t1.x * a1; pq0.y = t0.y * a0 + t1.y * a1;
    pq0.z = t0.z * a0 + t1.z * a1; pq0.w = t0.w * a0 + t1.w * a1;
    t0 = qtab[HID + c0]; t1 = qtab[HID + c1];
    pq1.x = t0.x * a0 + t1.x * a1; pq1.y = t0.y * a0 + t1.y * a1;
    pq1.z = t0.z * a0 + t1.z * a1; pq1.w = t0.w * a0 + t1.w * a1;
    t0 = ktab[c0]; t1 = ktab[c1];
    pk0.x = t0.x * a0 + t1.x * a1; pk0.y = t0.y * a0 + t1.y * a1;
    pk0.z = t0.z * a0 + t1.z * a1; pk0.w = t0.w * a0 + t1.w * a1;
    t0 = ktab[HID + c0]; t1 = ktab[HID + c1];
    pk1.x = t0.x * a0 + t1.x * a1; pk1.y = t0.y * a0 + t1.y * a1;
    pk1.z = t0.z * a0 + t1.z * a1; pk1.w = t0.w * a0 + t1.w * a1;
  }
#pragma unroll
  for (int off = 32; off > 0; off >>= 1) {
    pq0.x += __shfl_xor(pq0.x, off); pq0.y += __shfl_xor(pq0.y, off);
    pq0.z += __shfl_xor(pq0.z, off); pq0.w += __shfl_xor(pq0.w, off);
    pq1.x += __shfl_xor(pq1.x, off); pq1.y += __shfl_xor(pq1.y, off);
    pq1.z += __shfl_xor(pq1.z, off); pq1.w += __shfl_xor(pq1.w, off);
    pk0.x += __shfl_xor(pk0.x, off); pk0.y += __shfl_xor(pk0.y, off);
    pk0.z += __shfl_xor(pk0.z, off); pk0.w += __shfl_xor(pk0.w, off);
    pk1.x += __shfl_xor(pk1.x, off); pk1.y += __shfl_xor(pk1.y, off);
    pk1.z += __shfl_xor(pk1.z, off); pk1.w += __shfl_xor(pk1.w, off);
  }
  if (lane == 0) {
    qi4[n] = pq0; qi4[NPAD + n] = pq1;
    kj4[n] = pk0; kj4[NPAD + n] = pk1;
  }
}

// ---- fused per-dst-node: alpha -> segment softmax -> weighted aggregate ----
__global__ __launch_bounds__(256) void edge_fused_kernel(
    const int* __restrict__ rowstart, const int* __restrict__ eord,
    const float4* __restrict__ qi4, const float4* __restrict__ kj4,
    const unsigned short* __restrict__ xw, unsigned short* __restrict__ aggb) {
  __shared__ float wls[4][64][4];
  const int wave = threadIdx.x >> 6, lane = threadIdx.x & 63;
  const int n = blockIdx.x * 4 + wave;          // N_NODES % 4 == 0 -> always valid
  unsigned* outp = (unsigned*)(aggb + ((size_t)n << 7)) + lane;
  const int start = rowstart[n];
  const int deg = rowstart[n + 1] - start;
  if (deg == 0) { *outp = 0u; return; }
  const int hh = lane >> 4;
  const int ch2 = lane << 1;                    // ushort offset within a row
  float2 acc = {0.f, 0.f};
  float ssel;
  if (deg <= 64) {
    int p = 0;
    float a0 = -1e30f, a1 = -1e30f, a2 = -1e30f, a3 = -1e30f;
    if (lane < deg) {
      p = eord[start + lane];
      int s = p & 0xffff, r = p >> 16;
      float4 k4 = kj4[r ? (NPAD + s) : s];
      float4 q4 = r ? qi4[NPAD + n] : qi4[n];
      a0 = lrelu(q4.x + k4.x); a1 = lrelu(q4.y + k4.y);
      a2 = lrelu(q4.z + k4.z); a3 = lrelu(q4.w + k4.w);
    }
    float m0 = a0, m1 = a1, m2 = a2, m3 = a3;
#pragma unroll
    for (int off = 32; off > 0; off >>= 1) {
      m0 = fmaxf(m0, __shfl_xor(m0, off)); m1 = fmaxf(m1, __shfl_xor(m1, off));
      m2 = fmaxf(m2, __shfl_xor(m2, off)); m3 = fmaxf(m3, __shfl_xor(m3, off));
    }
    float w0 = 0.f, w1 = 0.f, w2 = 0.f, w3 = 0.f;
    if (lane < deg) {
      w0 = __expf(a0 - m0); w1 = __expf(a1 - m1);
      w2 = __expf(a2 - m2); w3 = __expf(a3 - m3);
    }
    float s0 = w0, s1 = w1, s2 = w2, s3 = w3;
#pragma unroll
    for (int off = 32; off > 0; off >>= 1) {
      s0 += __shfl_xor(s0, off); s1 += __shfl_xor(s1, off);
      s2 += __shfl_xor(s2, off); s3 += __shfl_xor(s3, off);
    }
    ssel = hh == 0 ? s0 : hh == 1 ? s1 : hh == 2 ? s2 : s3;
    // per-edge weights to LDS (volatile pins write->read ordering, wave-local)
    volatile float* wp = &wls[wave][lane][0];
    wp[0] = w0; wp[1] = w1; wp[2] = w2; wp[3] = w3;
    volatile float* wr = &wls[wave][0][0];
    const int degp = (deg + 3) & ~3;            // pad lanes hold w=0, p=0 (row 0)
    for (int e = 0; e < degp; e += 4) {
      int p0 = __builtin_amdgcn_readlane(p, e);
      int p1 = __builtin_amdgcn_readlane(p, e + 1);
      int p2 = __builtin_amdgcn_readlane(p, e + 2);
      int p3 = __builtin_amdgcn_readlane(p, e + 3);
      // scalar row bases -> SGPR-base loads with per-lane ch2 offset
      unsigned v0 = *(const unsigned*)(xw + ((size_t)((p0 & 0xffff) + (p0 >> 16) * NPAD) << 7) + ch2);
      unsigned v1 = *(const unsigned*)(xw + ((size_t)((p1 & 0xffff) + (p1 >> 16) * NPAD) << 7) + ch2);
      unsigned v2 = *(const unsigned*)(xw + ((size_t)((p2 & 0xffff) + (p2 >> 16) * NPAD) << 7) + ch2);
      unsigned v3 = *(const unsigned*)(xw + ((size_t)((p3 & 0xffff) + (p3 >> 16) * NPAD) << 7) + ch2);
      float we0 = wr[(e + 0) * 4 + hh];
      float we1 = wr[(e + 1) * 4 + hh];
      float we2 = wr[(e + 2) * 4 + hh];
      float we3 = wr[(e + 3) * 4 + hh];
      acc.x = fmaf(lo_f(v0), we0, acc.x); acc.y = fmaf(hi_f(v0), we0, acc.y);
      acc.x = fmaf(lo_f(v1), we1, acc.x); acc.y = fmaf(hi_f(v1), we1, acc.y);
      acc.x = fmaf(lo_f(v2), we2, acc.x); acc.y = fmaf(hi_f(v2), we2, acc.y);
      acc.x = fmaf(lo_f(v3), we3, acc.x); acc.y = fmaf(hi_f(v3), we3, acc.y);
    }
  } else {
    // ---- generic fallback (deg > 64): wave-uniform serial, rare ----
    const float4 q0 = qi4[n], q1 = qi4[NPAD + n];
    float4 m = make_float4(-1e30f, -1e30f, -1e30f, -1e30f);
    for (int e = start; e < start + deg; ++e) {
      int pe = eord[e];
      int s = pe & 0xffff, r = pe >> 16;
      float4 k4 = kj4[(size_t)r * NPAD + s];
      float4 q4 = r ? q1 : q0;
      m.x = fmaxf(m.x, lrelu(q4.x + k4.x)); m.y = fmaxf(m.y, lrelu(q4.y + k4.y));
      m.z = fmaxf(m.z, lrelu(q4.z + k4.z)); m.w = fmaxf(m.w, lrelu(q4.w + k4.w));
    }
    float4 sv = make_float4(0.f, 0.f, 0.f, 0.f);
    for (int e = start; e < start + deg; ++e) {
      int pe = eord[e];
      int s = pe & 0xffff, r = pe >> 16;
      float4 k4 = kj4[(size_t)r * NPAD + s];
      float4 q4 = r ? q1 : q0;
      float w0 = __expf(lrelu(q4.x + k4.x) - m.x);
      float w1 = __expf(lrelu(q4.y + k4.y) - m.y);
      float w2 = __expf(lrelu(q4.z + k4.z) - m.z);
      float w3 = __expf(lrelu(q4.w + k4.w) - m.w);
      sv.x += w0; sv.y += w1; sv.z += w2; sv.w += w3;
      float we = hh == 0 ? w0 : hh == 1 ? w1 : hh == 2 ? w2 : w3;
      unsigned v = *(const unsigned*)(xw + (((size_t)r * NPAD + s) << 7) + ch2);
      acc.x = fmaf(lo_f(v), we, acc.x);
      acc.y = fmaf(hi_f(v), we, acc.y);
    }
    ssel = hh == 0 ? sv.x : hh == 1 ? sv.y : hh == 2 ? sv.z : sv.w;
  }
  float inv = 1.f / (ssel + 1e-16f);
  *outp = (unsigned)f2bf_bits(acc.x * inv) | ((unsigned)f2bf_bits(acc.y * inv) << 16);
}

// ---- both layers: pWTb2[l][o][i] = bf16(pW[o][i]); bo2[l][o] = pb[o] + cb·pW[o,:] ----
__global__ __launch_bounds__(64) void prep_proj_kernel(const void* __restrict__ pW0,
                                                       const void* __restrict__ pW1,
                                                       const float* __restrict__ cbf,
                                                       const float* __restrict__ pbf,
                                                       unsigned short* __restrict__ pWTb2,
                                                       float* __restrict__ bo2,
                                                       const int* __restrict__ flags) {
  int o = blockIdx.x & 127, l = blockIdx.x >> 7, t = threadIdx.x;
  const void* pWraw = l ? pW1 : pW0;
  const float* cb = cbf + l * HID;
  const int f = flags[0];
  float part = 0.f;
#pragma unroll
  for (int i = t; i < HID; i += 64) {
    float w = f ? ((const float*)pWraw)[o * HID + i] : bf2f(((const unsigned short*)pWraw)[o * HID + i]);
    pWTb2[(size_t)l * HID * HID + o * HID + i] = f2bf_bits(w);
    part += cb[i] * w;
  }
#pragma unroll
  for (int off = 32; off > 0; off >>= 1) part += __shfl_xor(part, off);
  if (t == 0) bo2[l * HID + o] = pbf[l * HID + o] + part;
}

extern "C" void kernel_launch(void* const* d_in, const int* in_sizes, int n_in,
                              void* d_out, int out_size, void* d_ws, size_t ws_size,
                              hipStream_t stream) {
  const void* x     = d_in[0];
  const int*  eidx  = (const int*)d_in[1];
  const int*  etype = (const int*)d_in[2];
  const int iW[2] = {3, 9}, iQ[2] = {4, 10}, iK[2] = {5, 11}, icb[2] = {6, 12}, ipW[2] = {7, 13}, ipb[2] = {8, 14};

  float* ws = (float*)d_ws;
  size_t off = 0;
  int*   flags = (int*)(ws + off); off += 16;
  unsigned short* hb   = (unsigned short*)(ws + off); off += (size_t)NPAD * HID / 2;
  unsigned short* xw   = (unsigned short*)(ws + off); off += (size_t)NPAD * HID;       // [2][NPAD][128] bf16
  float* qi   = ws + off; off += (size_t)2 * NPAD * HEADS;
  float* kj   = ws + off; off += (size_t)2 * NPAD * HEADS;
  unsigned short* aggb = (unsigned short*)(ws + off); off += (size_t)NPAD * HID / 2;
  int* dstA = (int*)(ws + off); off += E_EDGES;
  int* pk   = (int*)(ws + off); off += E_EDGES;
  int* eord = (int*)(ws + off); off += E_EDGES;
  int* deg  = (int*)(ws + off); off += NPAD;        // deg|cnt contiguous for one zero pass
  int* cnt  = (int*)(ws + off); off += NPAD;
  int* excl = (int*)(ws + off); off += NPAD;
  int* rowstart = (int*)(ws + off); off += NPAD + 16;
  int* bsum  = (int*)(ws + off); off += 256;
  unsigned short* Wbt   = (unsigned short*)(ws + off); off += (size_t)2 * 2 * HID * HID / 2;
  unsigned short* pWTb2 = (unsigned short*)(ws + off); off += (size_t)2 * HID * HID / 2;
  float* qtab = ws + off; off += (size_t)2 * 2 * HID * 4;   // [l][r][128] float4
  float* ktab = ws + off; off += (size_t)2 * 2 * HID * 4;
  float* Qf  = ws + off; off += 2 * HID * HEADS;
  float* Kf  = ws + off; off += 2 * HID * HEADS;
  float* cbf = ws + off; off += 2 * HID;
  float* pbf = ws + off; off += 2 * HID;
  float* bo2 = ws + off; off += 2 * HID;

  // ---- detect + convert ----
  detect_kernel<<<1, 256, 0, stream>>>((const unsigned short*)x, eidx, flags);
  zero_int_kernel<<<(2 * NPAD + 255) / 256, 256, 0, stream>>>(deg, 2 * NPAD);   // deg + cnt
  cvt_idx_hist_kernel<<<(E_EDGES + 255) / 256, 256, 0, stream>>>(eidx, etype, dstA, pk, deg, flags);
  cvt_xb_kernel<<<(N_NODES * HID + 255) / 256, 256, 0, stream>>>(x, hb, N_NODES * HID, flags);
  cvt_wt_kernel<<<(2 * 2 * HID * HID + 255) / 256, 256, 0, stream>>>(d_in[iW[0]], d_in[iW[1]], Wbt, flags);
  {
    P8 tab;
    float* base = ws;
    for (int l = 0; l < 2; ++l) {
      tab.src[l * 4 + 0] = d_in[iQ[l]];  tab.dstoff[l * 4 + 0] = (int)(Qf - base) + l * HID * HEADS;  tab.n[l * 4 + 0] = HID * HEADS;
      tab.src[l * 4 + 1] = d_in[iK[l]];  tab.dstoff[l * 4 + 1] = (int)(Kf - base) + l * HID * HEADS;  tab.n[l * 4 + 1] = HID * HEADS;
      tab.src[l * 4 + 2] = d_in[icb[l]]; tab.dstoff[l * 4 + 2] = (int)(cbf - base) + l * HID;         tab.n[l * 4 + 2] = HID;
      tab.src[l * 4 + 3] = d_in[ipb[l]]; tab.dstoff[l * 4 + 3] = (int)(pbf - base) + l * HID;         tab.n[l * 4 + 3] = HID;
    }
    cvt_params_kernel<<<2, 256, 0, stream>>>(tab, base, flags);
  }

  // ---- counting sort by dst ----
  scan1_kernel<<<SCAN_B, 256, 0, stream>>>(deg, excl, bsum);
  scan23_kernel<<<SCAN_B, 256, 0, stream>>>(excl, bsum, rowstart);
  scatter_kernel<<<(E_EDGES + 255) / 256, 256, 0, stream>>>(dstA, pk, rowstart, cnt, eord);

  // ---- folded params ----
  prep_wq_kernel<<<2, 256, 0, stream>>>(Wbt, Qf, Kf, (float4*)qtab, (float4*)ktab);
  prep_proj_kernel<<<2 * HID, 64, 0, stream>>>(d_in[ipW[0]], d_in[ipW[1]], cbf, pbf, pWTb2, bo2, flags);

  const int RB = NPAD / 64;   // 782 row-blocks
  for (int l = 0; l < 2; ++l) {
    gemm_xw_mfma<<<RB, 256, 0, stream>>>(hb, Wbt + (size_t)l * 2 * HID * HID, xw);
    qk_direct_kernel<<<(N_NODES + 3) / 4, 256, 0, stream>>>(
        hb, (const float4*)(qtab + (size_t)l * 2 * HID * 4), (const float4*)(ktab + (size_t)l * 2 * HID * 4),
        (float4*)qi, (float4*)kj);
    edge_fused_kernel<<<N_NODES / 4, 256, 0, stream>>>(rowstart, eord, (const float4*)qi, (const float4*)kj, xw, aggb);
    proj_mfma<<<RB, 128, 0, stream>>>(aggb, pWTb2 + (size_t)l * HID * HID, bo2 + l * HID, hb,
                                      (l == 1) ? d_out : nullptr, flags);
  }
}

// Round 6
// 388.656 us; speedup vs baseline: 5.6369x; 1.2308x over previous
//
#include <hip/hip_runtime.h>
#include <hip/hip_bf16.h>

typedef __hip_bfloat16 bf16;
typedef short s16x8 __attribute__((ext_vector_type(8)));
typedef float f32x4 __attribute__((ext_vector_type(4)));

#define N_NODES 50000
#define NPAD    50048          // multiple of 64
#define E_EDGES 600000
#define HID     128
#define HEADS   4
#define SCAN_B  196            // ceil(NPAD/256)

// ---- float -> bf16 bits (RNE), finite inputs only ----
__device__ __forceinline__ unsigned short f2bf_bits(float f) {
  unsigned u = __float_as_uint(f);
  u += 0x7fffu + ((u >> 16) & 1u);
  return (unsigned short)(u >> 16);
}
__device__ __forceinline__ float bf2f(unsigned short b) {
  return __uint_as_float(((unsigned)b) << 16);
}
// packed-dword bf16 pair -> floats (1 op each)
__device__ __forceinline__ float lo_f(unsigned v) { return __uint_as_float(v << 16); }
__device__ __forceinline__ float hi_f(unsigned v) { return __uint_as_float(v & 0xffff0000u); }

__device__ __forceinline__ float lrelu(float v) { return v >= 0.f ? v : 0.2f * v; }

// ---- runtime dtype detection ----
// flags[0]=1 -> float tensors are fp32 (else bf16). flags[1]=1 -> indices are int64.
__global__ __launch_bounds__(256) void detect_kernel(const unsigned short* __restrict__ xb,
                                                     const int* __restrict__ ei,
                                                     int* __restrict__ flags) {
  int t = threadIdx.x;
  __shared__ int cnt[2];
  if (t < 2) cnt[t] = 0;
  __syncthreads();
  unsigned short v = xb[2 * t];
  int ex = (v >> 7) & 0xFF;
  if (ex < 119 || ex > 135) atomicAdd(&cnt[0], 1);
  if (ei[2 * t + 1] != 0) atomicAdd(&cnt[1], 1);
  __syncthreads();
  if (t == 0) {
    flags[0] = (cnt[0] > 64) ? 1 : 0;
    flags[1] = (cnt[1] == 0) ? 1 : 0;
  }
}

__global__ __launch_bounds__(256) void zero_int_kernel(int* __restrict__ p, int n) {
  int i = blockIdx.x * 256 + threadIdx.x;
  if (i < n) p[i] = 0;
}

// ---- index conversion + degree histogram: dstA[e], pk[e] = src | (r<<16) ----
__global__ __launch_bounds__(256) void cvt_idx_hist_kernel(const int* __restrict__ eidx,
                                                           const int* __restrict__ etype,
                                                           int* __restrict__ dstA, int* __restrict__ pk,
                                                           int* __restrict__ deg,
                                                           const int* __restrict__ flags) {
  int e = blockIdx.x * 256 + threadIdx.x;
  if (e >= E_EDGES) return;
  int s, d, r;
  if (flags[1]) {
    const long long* e64 = (const long long*)eidx;
    const long long* t64 = (const long long*)etype;
    s = (int)e64[e]; d = (int)e64[E_EDGES + e]; r = (int)t64[e];
  } else {
    s = eidx[e]; d = eidx[E_EDGES + e]; r = etype[e];
  }
  dstA[e] = d;
  pk[e] = s | (r << 16);
  atomicAdd(&deg[d], 1);
}

// ---- float-tensor -> bf16 bits ----
__global__ __launch_bounds__(256) void cvt_xb_kernel(const void* __restrict__ src,
                                                     unsigned short* __restrict__ dst, int n,
                                                     const int* __restrict__ flags) {
  int i = blockIdx.x * 256 + threadIdx.x;
  if (i >= n) return;
  if (flags[0]) dst[i] = f2bf_bits(((const float*)src)[i]);
  else          dst[i] = ((const unsigned short*)src)[i];
}

// ---- W (both layers) [128(in)][128(out)] -> bf16 N-major [l][r][o][i] ----
__global__ __launch_bounds__(256) void cvt_wt_kernel(const void* __restrict__ src0,
                                                     const void* __restrict__ src1,
                                                     unsigned short* __restrict__ dst,
                                                     const int* __restrict__ flags) {
  int idx = blockIdx.x * 256 + threadIdx.x;
  if (idx >= 2 * 2 * HID * HID) return;
  int l = idx >> 15, rem = idx & 32767;
  int r = rem >> 14, i = (rem >> 7) & 127, o = rem & 127;
  const void* src = l ? src1 : src0;
  unsigned short b;
  if (flags[0]) b = f2bf_bits(((const float*)src)[rem]);
  else          b = ((const unsigned short*)src)[rem];
  dst[(size_t)l * 2 * HID * HID + ((size_t)r * HID + o) * HID + i] = b;
}

// ---- small params (Q,K,cb,pb for both layers) -> fp32 block ----
struct P8 { const void* src[8]; int dstoff[8]; int n[8]; };
__global__ __launch_bounds__(256) void cvt_params_kernel(P8 tab, float* __restrict__ base,
                                                         const int* __restrict__ flags) {
  const int f = flags[0];
  for (int k = 0; k < 8; ++k) {
    int n = tab.n[k];
    for (int i = blockIdx.x * 256 + threadIdx.x; i < n; i += gridDim.x * 256) {
      float v = f ? ((const float*)tab.src[k])[i] : bf2f(((const unsigned short*)tab.src[k])[i]);
      base[tab.dstoff[k] + i] = v;
    }
  }
}

// ---- scan stage 1: per-256-block inclusive scan ----
__global__ __launch_bounds__(256) void scan1_kernel(const int* __restrict__ deg,
                                                    int* __restrict__ excl,
                                                    int* __restrict__ bsum) {
  __shared__ int sm[256];
  int t = threadIdx.x, i = blockIdx.x * 256 + t;
  int v = (i < NPAD) ? deg[i] : 0;
  sm[t] = v;
  __syncthreads();
#pragma unroll
  for (int off = 1; off < 256; off <<= 1) {
    int add = (t >= off) ? sm[t - off] : 0;
    __syncthreads();
    sm[t] += add;
    __syncthreads();
  }
  if (i < NPAD) excl[i] = sm[t] - v;
  if (t == 255) bsum[blockIdx.x] = sm[255];
}

// ---- scan stages 2+3 fused: each block redundantly scans bsum, adds prefix ----
__global__ __launch_bounds__(256) void scan23_kernel(const int* __restrict__ excl,
                                                     const int* __restrict__ bsum,
                                                     int* __restrict__ rowstart) {
  __shared__ int sm[256];
  int t = threadIdx.x;
  int v = (t < SCAN_B) ? bsum[t] : 0;
  sm[t] = v;
  __syncthreads();
#pragma unroll
  for (int off = 1; off < 256; off <<= 1) {
    int add = (t >= off) ? sm[t - off] : 0;
    __syncthreads();
    sm[t] += add;
    __syncthreads();
  }
  int bpre = (blockIdx.x > 0) ? sm[blockIdx.x - 1] : 0;   // exclusive block prefix
  int i = blockIdx.x * 256 + t;
  if (i < NPAD) rowstart[i] = excl[i] + bpre;
  if (i == 0) rowstart[NPAD] = E_EDGES;
}

__global__ __launch_bounds__(256) void scatter_kernel(const int* __restrict__ dstA,
                                                      const int* __restrict__ pk,
                                                      const int* __restrict__ rowstart,
                                                      int* __restrict__ cnt,
                                                      int* __restrict__ eord) {
  int e = blockIdx.x * 256 + threadIdx.x;
  if (e >= E_EDGES) return;
  int d = dstA[e];
  int pos = rowstart[d] + atomicAdd(&cnt[d], 1);
  eord[pos] = pk[e];
}

// ================= MFMA GEMM core: one wave -> 64 rows x 64 cols, K=128 ======
__device__ __forceinline__ void wave_gemm64(const unsigned short* __restrict__ Ab, int row0,
                                            const unsigned short* __restrict__ Bt, int colb,
                                            int lane, f32x4 acc[4][4]) {
  const int lm = lane & 15, q = lane >> 4;
#pragma unroll
  for (int kc = 0; kc < 4; ++kc) {
    const int ko = kc * 32 + q * 8;
    s16x8 af[4], bfr[4];
#pragma unroll
    for (int rt = 0; rt < 4; ++rt)
      af[rt] = *(const s16x8*)(Ab + (size_t)(row0 + rt * 16 + lm) * HID + ko);
#pragma unroll
    for (int ct = 0; ct < 4; ++ct)
      bfr[ct] = *(const s16x8*)(Bt + (size_t)(colb + ct * 16 + lm) * HID + ko);
#pragma unroll
    for (int rt = 0; rt < 4; ++rt)
#pragma unroll
      for (int ct = 0; ct < 4; ++ct)
        acc[rt][ct] = __builtin_amdgcn_mfma_f32_16x16x32_bf16(af[rt], bfr[ct], acc[rt][ct], 0, 0, 0);
  }
}

// ---- xw[r,n,:] = h[n,:] @ W[r]; block = 4 waves = 4 (r,colpanel) of SAME rows ----
__global__ __launch_bounds__(256) void gemm_xw_mfma(const unsigned short* __restrict__ hb,
                                                    const unsigned short* __restrict__ Wbt,
                                                    unsigned short* __restrict__ xw) {
  const int wave = threadIdx.x >> 6, lane = threadIdx.x & 63;
  const int row0 = blockIdx.x * 64;
  const int r = wave >> 1, colb = (wave & 1) * 64;
  f32x4 acc[4][4];
#pragma unroll
  for (int a = 0; a < 4; ++a)
#pragma unroll
    for (int b = 0; b < 4; ++b) { f32x4 z = {0.f, 0.f, 0.f, 0.f}; acc[a][b] = z; }
  wave_gemm64(hb, row0, Wbt + (size_t)r * HID * HID, colb, lane, acc);
  const int lm = lane & 15, q = lane >> 4;
#pragma unroll
  for (int rt = 0; rt < 4; ++rt)
#pragma unroll
    for (int i = 0; i < 4; ++i) {
      int row = row0 + rt * 16 + q * 4 + i;
      if (row < N_NODES) {
#pragma unroll
        for (int ct = 0; ct < 4; ++ct) {
          int o = colb + ct * 16 + lm;
          xw[((size_t)r * NPAD + row) * HID + o] = f2bf_bits(acc[rt][ct][i]);
        }
      }
    }
}

// ---- out[n,o] = elu( agg[n,:] @ pW.T + bo ); block = 2 waves = 2 col panels ----
__global__ __launch_bounds__(128) void proj_mfma(const unsigned short* __restrict__ aggb,
                                                 const unsigned short* __restrict__ pWTb,
                                                 const float* __restrict__ bo,
                                                 unsigned short* __restrict__ hbout,
                                                 void* __restrict__ dout,
                                                 const int* __restrict__ flags) {
  const int wave = threadIdx.x >> 6, lane = threadIdx.x & 63;
  const int row0 = blockIdx.x * 64;
  const int colb = wave * 64;
  f32x4 acc[4][4];
#pragma unroll
  for (int a = 0; a < 4; ++a)
#pragma unroll
    for (int b = 0; b < 4; ++b) { f32x4 z = {0.f, 0.f, 0.f, 0.f}; acc[a][b] = z; }
  wave_gemm64(aggb, row0, pWTb, colb, lane, acc);
  const int lm = lane & 15, q = lane >> 4;
  const int f32out = flags[0];
#pragma unroll
  for (int rt = 0; rt < 4; ++rt)
#pragma unroll
    for (int i = 0; i < 4; ++i) {
      int row = row0 + rt * 16 + q * 4 + i;
      if (row < N_NODES) {
#pragma unroll
        for (int ct = 0; ct < 4; ++ct) {
          int o = colb + ct * 16 + lm;
          float v = acc[rt][ct][i] + bo[o];
          v = v > 0.f ? v : expm1f(v);       // ELU
          size_t idx = (size_t)row * HID + o;
          if (dout) {
            if (f32out) ((float*)dout)[idx] = v;
            else        ((unsigned short*)dout)[idx] = f2bf_bits(v);
          } else {
            hbout[idx] = f2bf_bits(v);
          }
        }
      }
    }
}

// ---- WQ/WK fold -> split-bf16 table qkt[l][out16][128], out = qk*8 + r*4 + h ----
__global__ __launch_bounds__(256) void prep_wq_kernel(const unsigned short* __restrict__ Wbt,
                                                      const float* __restrict__ Qf,
                                                      const float* __restrict__ Kf,
                                                      unsigned short* __restrict__ qkt_hi,
                                                      unsigned short* __restrict__ qkt_lo) {
  int idx = blockIdx.x * 256 + threadIdx.x;   // (l,r,i)
  if (idx >= 2 * 2 * HID) return;
  int i = idx & 127, lr = idx >> 7, l = lr >> 1, r = (lr & 1);
  float aq[4] = {0.f, 0.f, 0.f, 0.f}, ak[4] = {0.f, 0.f, 0.f, 0.f};
  const unsigned short* Wb = Wbt + (size_t)lr * HID * HID;   // [o=j][i]
  const float* Qp = Qf + l * HID * HEADS;
  const float* Kp = Kf + l * HID * HEADS;
  for (int j = 0; j < HID; ++j) {
    float w = bf2f(Wb[j * HID + i]);
    float4 q4 = *(const float4*)(Qp + j * 4);
    float4 k4 = *(const float4*)(Kp + j * 4);
    aq[0] += w * q4.x; aq[1] += w * q4.y; aq[2] += w * q4.z; aq[3] += w * q4.w;
    ak[0] += w * k4.x; ak[1] += w * k4.y; ak[2] += w * k4.z; ak[3] += w * k4.w;
  }
  size_t base = (size_t)l * 16 * HID;
#pragma unroll
  for (int h = 0; h < 4; ++h) {
    // q: out = r*4+h ; k: out = 8 + r*4+h
    unsigned short qh = f2bf_bits(aq[h]);
    unsigned short kh = f2bf_bits(ak[h]);
    float qres = aq[h] - bf2f(qh);
    float kres = ak[h] - bf2f(kh);
    qkt_hi[base + (size_t)(r * 4 + h) * HID + i] = qh;
    qkt_lo[base + (size_t)(r * 4 + h) * HID + i] = f2bf_bits(qres);
    qkt_hi[base + (size_t)(8 + r * 4 + h) * HID + i] = kh;
    qkt_lo[base + (size_t)(8 + r * 4 + h) * HID + i] = f2bf_bits(kres);
  }
}

// ---- qk via MFMA: [64 nodes]x[16 outs] per wave, split-bf16 B for fp32 accuracy ----
__global__ __launch_bounds__(256) void qk_mfma_kernel(const unsigned short* __restrict__ hb,
                                                      const unsigned short* __restrict__ qkt_hi,
                                                      const unsigned short* __restrict__ qkt_lo,
                                                      float4* __restrict__ qi4,
                                                      float4* __restrict__ kj4) {
  __shared__ float st[4][16][68];               // [wave][out][node], pad 68 -> conflict-free reads
  const int wave = threadIdx.x >> 6, lane = threadIdx.x & 63;
  const int row0 = blockIdx.x * 256 + wave * 64;
  const int lm = lane & 15, q = lane >> 4;
  if (row0 < NPAD) {
    f32x4 acc[4];
#pragma unroll
    for (int a = 0; a < 4; ++a) { f32x4 z = {0.f, 0.f, 0.f, 0.f}; acc[a] = z; }
#pragma unroll
    for (int kc = 0; kc < 4; ++kc) {
      const int ko = kc * 32 + q * 8;
      s16x8 bhi = *(const s16x8*)(qkt_hi + (size_t)lm * HID + ko);
      s16x8 blo = *(const s16x8*)(qkt_lo + (size_t)lm * HID + ko);
#pragma unroll
      for (int rt = 0; rt < 4; ++rt) {
        s16x8 af = *(const s16x8*)(hb + (size_t)(row0 + rt * 16 + lm) * HID + ko);
        acc[rt] = __builtin_amdgcn_mfma_f32_16x16x32_bf16(af, bhi, acc[rt], 0, 0, 0);
        acc[rt] = __builtin_amdgcn_mfma_f32_16x16x32_bf16(af, blo, acc[rt], 0, 0, 0);
      }
    }
    // C layout: col(out)=lm, row(node)=rt*16 + q*4 + i -> stage [out][node] in LDS
#pragma unroll
    for (int rt = 0; rt < 4; ++rt)
      *(f32x4*)&st[wave][lm][rt * 16 + q * 4] = acc[rt];
  }
  __syncthreads();
  if (row0 < NPAD) {
    int n = row0 + lane;
    if (n < N_NODES) {
      float4 v;
      v.x = st[wave][0][lane]; v.y = st[wave][1][lane]; v.z = st[wave][2][lane]; v.w = st[wave][3][lane];
      qi4[n] = v;
      v.x = st[wave][4][lane]; v.y = st[wave][5][lane]; v.z = st[wave][6][lane]; v.w = st[wave][7][lane];
      qi4[NPAD + n] = v;
      v.x = st[wave][8][lane]; v.y = st[wave][9][lane]; v.z = st[wave][10][lane]; v.w = st[wave][11][lane];
      kj4[n] = v;
      v.x = st[wave][12][lane]; v.y = st[wave][13][lane]; v.z = st[wave][14][lane]; v.w = st[wave][15][lane];
      kj4[NPAD + n] = v;
    }
  }
}

// ---- fused per-dst-node: alpha -> segment softmax -> weighted aggregate ----
__global__ __launch_bounds__(256) void edge_fused_kernel(
    const int* __restrict__ rowstart, const int* __restrict__ eord,
    const float4* __restrict__ qi4, const float4* __restrict__ kj4,
    const unsigned short* __restrict__ xw, unsigned short* __restrict__ aggb) {
  __shared__ float wls[4][64][4];
  const int wave = threadIdx.x >> 6, lane = threadIdx.x & 63;
  const int n = blockIdx.x * 4 + wave;          // N_NODES % 4 == 0 -> always valid
  unsigned* outp = (unsigned*)(aggb + ((size_t)n << 7)) + lane;
  const int start = rowstart[n];
  const int deg = rowstart[n + 1] - start;
  if (deg == 0) { *outp = 0u; return; }
  const int hh = lane >> 4;
  const int ch2 = lane << 1;                    // ushort offset within a row
  float2 acc = {0.f, 0.f};
  float ssel;
  if (deg <= 64) {
    int p = 0;
    float a0 = -1e30f, a1 = -1e30f, a2 = -1e30f, a3 = -1e30f;
    if (lane < deg) {
      p = eord[start + lane];
      int s = p & 0xffff, r = p >> 16;
      float4 k4 = kj4[r ? (NPAD + s) : s];
      float4 q4 = r ? qi4[NPAD + n] : qi4[n];
      a0 = lrelu(q4.x + k4.x); a1 = lrelu(q4.y + k4.y);
      a2 = lrelu(q4.z + k4.z); a3 = lrelu(q4.w + k4.w);
    }
    float m0 = a0, m1 = a1, m2 = a2, m3 = a3;
#pragma unroll
    for (int off = 32; off > 0; off >>= 1) {
      m0 = fmaxf(m0, __shfl_xor(m0, off)); m1 = fmaxf(m1, __shfl_xor(m1, off));
      m2 = fmaxf(m2, __shfl_xor(m2, off)); m3 = fmaxf(m3, __shfl_xor(m3, off));
    }
    float w0 = 0.f, w1 = 0.f, w2 = 0.f, w3 = 0.f;
    if (lane < deg) {
      w0 = __expf(a0 - m0); w1 = __expf(a1 - m1);
      w2 = __expf(a2 - m2); w3 = __expf(a3 - m3);
    }
    float s0 = w0, s1 = w1, s2 = w2, s3 = w3;
#pragma unroll
    for (int off = 32; off > 0; off >>= 1) {
      s0 += __shfl_xor(s0, off); s1 += __shfl_xor(s1, off);
      s2 += __shfl_xor(s2, off); s3 += __shfl_xor(s3, off);
    }
    ssel = hh == 0 ? s0 : hh == 1 ? s1 : hh == 2 ? s2 : s3;
    // per-edge weights to LDS (volatile pins write->read ordering, wave-local)
    volatile float* wp = &wls[wave][lane][0];
    wp[0] = w0; wp[1] = w1; wp[2] = w2; wp[3] = w3;
    volatile float* wr = &wls[wave][0][0];
    const int degp = (deg + 3) & ~3;            // pad lanes hold w=0, p=0 (row 0)
    for (int e = 0; e < degp; e += 4) {
      int p0 = __builtin_amdgcn_readlane(p, e);
      int p1 = __builtin_amdgcn_readlane(p, e + 1);
      int p2 = __builtin_amdgcn_readlane(p, e + 2);
      int p3 = __builtin_amdgcn_readlane(p, e + 3);
      // scalar row bases -> SGPR-base loads with per-lane ch2 offset
      unsigned v0 = *(const unsigned*)(xw + ((size_t)((p0 & 0xffff) + (p0 >> 16) * NPAD) << 7) + ch2);
      unsigned v1 = *(const unsigned*)(xw + ((size_t)((p1 & 0xffff) + (p1 >> 16) * NPAD) << 7) + ch2);
      unsigned v2 = *(const unsigned*)(xw + ((size_t)((p2 & 0xffff) + (p2 >> 16) * NPAD) << 7) + ch2);
      unsigned v3 = *(const unsigned*)(xw + ((size_t)((p3 & 0xffff) + (p3 >> 16) * NPAD) << 7) + ch2);
      float we0 = wr[(e + 0) * 4 + hh];
      float we1 = wr[(e + 1) * 4 + hh];
      float we2 = wr[(e + 2) * 4 + hh];
      float we3 = wr[(e + 3) * 4 + hh];
      acc.x = fmaf(lo_f(v0), we0, acc.x); acc.y = fmaf(hi_f(v0), we0, acc.y);
      acc.x = fmaf(lo_f(v1), we1, acc.x); acc.y = fmaf(hi_f(v1), we1, acc.y);
      acc.x = fmaf(lo_f(v2), we2, acc.x); acc.y = fmaf(hi_f(v2), we2, acc.y);
      acc.x = fmaf(lo_f(v3), we3, acc.x); acc.y = fmaf(hi_f(v3), we3, acc.y);
    }
  } else {
    // ---- generic fallback (deg > 64): wave-uniform serial, rare ----
    const float4 q0 = qi4[n], q1 = qi4[NPAD + n];
    float4 m = make_float4(-1e30f, -1e30f, -1e30f, -1e30f);
    for (int e = start; e < start + deg; ++e) {
      int pe = eord[e];
      int s = pe & 0xffff, r = pe >> 16;
      float4 k4 = kj4[(size_t)r * NPAD + s];
      float4 q4 = r ? q1 : q0;
      m.x = fmaxf(m.x, lrelu(q4.x + k4.x)); m.y = fmaxf(m.y, lrelu(q4.y + k4.y));
      m.z = fmaxf(m.z, lrelu(q4.z + k4.z)); m.w = fmaxf(m.w, lrelu(q4.w + k4.w));
    }
    float4 sv = make_float4(0.f, 0.f, 0.f, 0.f);
    for (int e = start; e < start + deg; ++e) {
      int pe = eord[e];
      int s = pe & 0xffff, r = pe >> 16;
      float4 k4 = kj4[(size_t)r * NPAD + s];
      float4 q4 = r ? q1 : q0;
      float w0 = __expf(lrelu(q4.x + k4.x) - m.x);
      float w1 = __expf(lrelu(q4.y + k4.y) - m.y);
      float w2 = __expf(lrelu(q4.z + k4.z) - m.z);
      float w3 = __expf(lrelu(q4.w + k4.w) - m.w);
      sv.x += w0; sv.y += w1; sv.z += w2; sv.w += w3;
      float we = hh == 0 ? w0 : hh == 1 ? w1 : hh == 2 ? w2 : w3;
      unsigned v = *(const unsigned*)(xw + (((size_t)r * NPAD + s) << 7) + ch2);
      acc.x = fmaf(lo_f(v), we, acc.x);
      acc.y = fmaf(hi_f(v), we, acc.y);
    }
    ssel = hh == 0 ? sv.x : hh == 1 ? sv.y : hh == 2 ? sv.z : sv.w;
  }
  float inv = 1.f / (ssel + 1e-16f);
  *outp = (unsigned)f2bf_bits(acc.x * inv) | ((unsigned)f2bf_bits(acc.y * inv) << 16);
}

// ---- both layers: pWTb2[l][o][i] = bf16(pW[o][i]); bo2[l][o] = pb[o] + cb·pW[o,:] ----
__global__ __launch_bounds__(64) void prep_proj_kernel(const void* __restrict__ pW0,
                                                       const void* __restrict__ pW1,
                                                       const float* __restrict__ cbf,
                                                       const float* __restrict__ pbf,
                                                       unsigned short* __restrict__ pWTb2,
                                                       float* __restrict__ bo2,
                                                       const int* __restrict__ flags) {
  int o = blockIdx.x & 127, l = blockIdx.x >> 7, t = threadIdx.x;
  const void* pWraw = l ? pW1 : pW0;
  const float* cb = cbf + l * HID;
  const int f = flags[0];
  float part = 0.f;
#pragma unroll
  for (int i = t; i < HID; i += 64) {
    float w = f ? ((const float*)pWraw)[o * HID + i] : bf2f(((const unsigned short*)pWraw)[o * HID + i]);
    pWTb2[(size_t)l * HID * HID + o * HID + i] = f2bf_bits(w);
    part += cb[i] * w;
  }
#pragma unroll
  for (int off = 32; off > 0; off >>= 1) part += __shfl_xor(part, off);
  if (t == 0) bo2[l * HID + o] = pbf[l * HID + o] + part;
}

extern "C" void kernel_launch(void* const* d_in, const int* in_sizes, int n_in,
                              void* d_out, int out_size, void* d_ws, size_t ws_size,
                              hipStream_t stream) {
  const void* x     = d_in[0];
  const int*  eidx  = (const int*)d_in[1];
  const int*  etype = (const int*)d_in[2];
  const int iW[2] = {3, 9}, iQ[2] = {4, 10}, iK[2] = {5, 11}, icb[2] = {6, 12}, ipW[2] = {7, 13}, ipb[2] = {8, 14};

  float* ws = (float*)d_ws;
  size_t off = 0;
  int*   flags = (int*)(ws + off); off += 16;
  unsigned short* hb   = (unsigned short*)(ws + off); off += (size_t)NPAD * HID / 2;
  unsigned short* xw   = (unsigned short*)(ws + off); off += (size_t)NPAD * HID;       // [2][NPAD][128] bf16
  float* qi   = ws + off; off += (size_t)2 * NPAD * HEADS;
  float* kj   = ws + off; off += (size_t)2 * NPAD * HEADS;
  unsigned short* aggb = (unsigned short*)(ws + off); off += (size_t)NPAD * HID / 2;
  int* dstA = (int*)(ws + off); off += E_EDGES;
  int* pk   = (int*)(ws + off); off += E_EDGES;
  int* eord = (int*)(ws + off); off += E_EDGES;
  int* deg  = (int*)(ws + off); off += NPAD;        // deg|cnt contiguous for one zero pass
  int* cnt  = (int*)(ws + off); off += NPAD;
  int* excl = (int*)(ws + off); off += NPAD;
  int* rowstart = (int*)(ws + off); off += NPAD + 16;
  int* bsum  = (int*)(ws + off); off += 256;
  unsigned short* Wbt   = (unsigned short*)(ws + off); off += (size_t)2 * 2 * HID * HID / 2;
  unsigned short* pWTb2 = (unsigned short*)(ws + off); off += (size_t)2 * HID * HID / 2;
  unsigned short* qkt_hi = (unsigned short*)(ws + off); off += (size_t)2 * 16 * HID / 2;
  unsigned short* qkt_lo = (unsigned short*)(ws + off); off += (size_t)2 * 16 * HID / 2;
  float* Qf  = ws + off; off += 2 * HID * HEADS;
  float* Kf  = ws + off; off += 2 * HID * HEADS;
  float* cbf = ws + off; off += 2 * HID;
  float* pbf = ws + off; off += 2 * HID;
  float* bo2 = ws + off; off += 2 * HID;

  // ---- detect + convert ----
  detect_kernel<<<1, 256, 0, stream>>>((const unsigned short*)x, eidx, flags);
  zero_int_kernel<<<(2 * NPAD + 255) / 256, 256, 0, stream>>>(deg, 2 * NPAD);   // deg + cnt
  cvt_idx_hist_kernel<<<(E_EDGES + 255) / 256, 256, 0, stream>>>(eidx, etype, dstA, pk, deg, flags);
  cvt_xb_kernel<<<(N_NODES * HID + 255) / 256, 256, 0, stream>>>(x, hb, N_NODES * HID, flags);
  cvt_wt_kernel<<<(2 * 2 * HID * HID + 255) / 256, 256, 0, stream>>>(d_in[iW[0]], d_in[iW[1]], Wbt, flags);
  {
    P8 tab;
    float* base = ws;
    for (int l = 0; l < 2; ++l) {
      tab.src[l * 4 + 0] = d_in[iQ[l]];  tab.dstoff[l * 4 + 0] = (int)(Qf - base) + l * HID * HEADS;  tab.n[l * 4 + 0] = HID * HEADS;
      tab.src[l * 4 + 1] = d_in[iK[l]];  tab.dstoff[l * 4 + 1] = (int)(Kf - base) + l * HID * HEADS;  tab.n[l * 4 + 1] = HID * HEADS;
      tab.src[l * 4 + 2] = d_in[icb[l]]; tab.dstoff[l * 4 + 2] = (int)(cbf - base) + l * HID;         tab.n[l * 4 + 2] = HID;
      tab.src[l * 4 + 3] = d_in[ipb[l]]; tab.dstoff[l * 4 + 3] = (int)(pbf - base) + l * HID;         tab.n[l * 4 + 3] = HID;
    }
    cvt_params_kernel<<<2, 256, 0, stream>>>(tab, base, flags);
  }

  // ---- counting sort by dst ----
  scan1_kernel<<<SCAN_B, 256, 0, stream>>>(deg, excl, bsum);
  scan23_kernel<<<SCAN_B, 256, 0, stream>>>(excl, bsum, rowstart);
  scatter_kernel<<<(E_EDGES + 255) / 256, 256, 0, stream>>>(dstA, pk, rowstart, cnt, eord);

  // ---- folded params ----
  prep_wq_kernel<<<2, 256, 0, stream>>>(Wbt, Qf, Kf, qkt_hi, qkt_lo);
  prep_proj_kernel<<<2 * HID, 64, 0, stream>>>(d_in[ipW[0]], d_in[ipW[1]], cbf, pbf, pWTb2, bo2, flags);

  const int RB = NPAD / 64;   // 782 row-blocks
  const int QB = (NPAD + 255) / 256;
  for (int l = 0; l < 2; ++l) {
    gemm_xw_mfma<<<RB, 256, 0, stream>>>(hb, Wbt + (size_t)l * 2 * HID * HID, xw);
    qk_mfma_kernel<<<QB, 256, 0, stream>>>(hb, qkt_hi + (size_t)l * 16 * HID, qkt_lo + (size_t)l * 16 * HID,
                                           (float4*)qi, (float4*)kj);
    edge_fused_kernel<<<N_NODES / 4, 256, 0, stream>>>(rowstart, eord, (const float4*)qi, (const float4*)kj, xw, aggb);
    proj_mfma<<<RB, 128, 0, stream>>>(aggb, pWTb2 + (size_t)l * HID * HID, bo2 + l * HID, hb,
                                      (l == 1) ? d_out : nullptr, flags);
  }
}